// Round 1
// baseline (15363.728 us; speedup 1.0000x reference)
//
#include <hip/hip_runtime.h>
#include <cstdint>

// CharRNN: 2-layer LSTM, B=32, T=256, H=1024, V=256, teacher forcing.
// Strategy:
//   - E0[v][j'] = emb[v] @ W_ih0 + b0  (vocab is tiny: 256 rows) -> gather per step
//   - recurrent GEMMs with gate-interleaved weights W'[k][u*4+g], fused LSTM cell
//   - h1 for all t stored; final logits = h1_all @ W_out + b_out (one big GEMM)
// Workspace requirement: ~106 MB.

static constexpr int BB = 32;     // batch
static constexpr int TT = 256;    // time
static constexpr int HH = 1024;   // hidden
static constexpr int VV = 256;    // vocab
static constexpr int HG = 4096;   // 4*H

// ---------------- transpose W[k][g*H+u] -> W'[k][u*4+g] ----------------
__global__ void transpose_gates(const float* __restrict__ in, float* __restrict__ out) {
    int idx = blockIdx.x * 256 + threadIdx.x;   // 0 .. 1024*1024
    int k = idx >> 10;
    int u = idx & 1023;
    float4 v;
    v.x = in[k * HG + 0 * HH + u];
    v.y = in[k * HG + 1 * HH + u];
    v.z = in[k * HG + 2 * HH + u];
    v.w = in[k * HG + 3 * HH + u];
    *reinterpret_cast<float4*>(&out[k * HG + u * 4]) = v;
}

__global__ void interleave_bias(const float* __restrict__ b0, const float* __restrict__ b1,
                                float* __restrict__ b0i, float* __restrict__ b1i) {
    int j = blockIdx.x * 256 + threadIdx.x;     // 0..4095 (j' = u*4+g)
    int u = j >> 2, g = j & 3;
    b0i[j] = b0[g * HH + u];
    b1i[j] = b1[g * HH + u];
}

__global__ void init_states(const float* __restrict__ h0, const float* __restrict__ c0,
                            const float* __restrict__ h1, const float* __restrict__ c1,
                            float* __restrict__ h0A, float* __restrict__ c0w,
                            float* __restrict__ h1A, float* __restrict__ c1w) {
    int idx = blockIdx.x * 256 + threadIdx.x;   // 0..131071
    int off = idx & 32767;
    switch (idx >> 15) {
        case 0: h0A[off] = h0[off]; break;
        case 1: c0w[off] = c0[off]; break;
        case 2: h1A[off] = h1[off]; break;
        case 3: c1w[off] = c1[off]; break;
    }
}

__global__ void copy_finals(const float* __restrict__ h0A, const float* __restrict__ c0,
                            const float* __restrict__ h1A, const float* __restrict__ c1,
                            float* __restrict__ out) {
    int idx = blockIdx.x * 256 + threadIdx.x;   // 0..131071
    int off = idx & 32767;
    const float* src;
    switch (idx >> 15) {
        case 0: src = h0A; break;
        case 1: src = c0;  break;
        case 2: src = h1A; break;
        default: src = c1; break;
    }
    out[idx] = src[off];
}

// ---------------- generic tiled GEMM with bias: C[M][N] = A[M][K]@B[K][N] + bias ----------------
__global__ __launch_bounds__(256) void gemm_bias(const float* __restrict__ A,
                                                 const float* __restrict__ Bm,
                                                 const float* __restrict__ bias,
                                                 float* __restrict__ C,
                                                 int M, int N, int K) {
    constexpr int BM = 64, BN = 64, BK = 16, TM = 4, TN = 4;
    __shared__ float As[BK][BM + 1];
    __shared__ float Bs[BK][BN + 1];
    int tx = threadIdx.x % (BN / TN);   // 16
    int ty = threadIdx.x / (BN / TN);   // 16
    int rowBase = blockIdx.y * BM, colBase = blockIdx.x * BN;
    float acc[TM][TN] = {};
    for (int k0 = 0; k0 < K; k0 += BK) {
        for (int i = threadIdx.x; i < BM * BK; i += 256) {
            int r = i / BK, c = i % BK;
            As[c][r] = A[(rowBase + r) * K + k0 + c];
        }
        for (int i = threadIdx.x; i < BK * BN; i += 256) {
            int r = i / BN, c = i % BN;
            Bs[r][c] = Bm[(k0 + r) * N + colBase + c];
        }
        __syncthreads();
        #pragma unroll
        for (int kk = 0; kk < BK; ++kk) {
            float av[TM];
            #pragma unroll
            for (int i = 0; i < TM; ++i) av[i] = As[kk][ty * TM + i];
            #pragma unroll
            for (int i = 0; i < TM; ++i)
                #pragma unroll
                for (int j = 0; j < TN; ++j)
                    acc[i][j] += av[i] * Bs[kk][tx * TN + j];
        }
        __syncthreads();
    }
    #pragma unroll
    for (int i = 0; i < TM; ++i)
        #pragma unroll
        for (int j = 0; j < TN; ++j) {
            int r = rowBase + ty * TM + i, c = colBase + tx * TN + j;
            C[r * N + c] = acc[i][j] + bias[c];
        }
}

// ---------------- fused recurrent step kernel ----------------
// Computes z[b][j'] = sum_k hin1[b][k]*W1T[k][j'] (+ hin2@W2T if L1)
//                   + (L1 ? b1i[j'] : E0[tgt[b][t]][j'])
// then the LSTM cell for the 4 gates of each unit, updating c in place,
// writing new h to hout (ping-pong), and (L1) saving h to h1all.
// Grid: 256 wgs (16 j'-columns = 4 units each), 512 threads.
template <bool L1>
__global__ __launch_bounds__(512) void lstm_step(
        const float* __restrict__ W1T, const float* __restrict__ hin1,
        const float* __restrict__ W2T, const float* __restrict__ hin2,
        const float* __restrict__ E0,  const float* __restrict__ bI,
        const int* __restrict__ tgt,
        float* __restrict__ cio, float* __restrict__ hout,
        float* __restrict__ h1all, int t) {
    __shared__ float hs[256][36];     // h chunk, transposed [k][b], padded; 36.9 KB (reused for reduction)
    const int tid = threadIdx.x;
    const int ks  = tid >> 5;         // 0..15: K-split slice
    const int sub = tid & 31;
    const int lj  = sub & 3;          // j-quad within block
    const int bb  = sub >> 2;         // 0..7: batch quad
    const int jbase = blockIdx.x << 4;
    const int j4 = jbase + (lj << 2);

    float acc[16];
    #pragma unroll
    for (int i = 0; i < 16; ++i) acc[i] = 0.f;

    const int nmat = L1 ? 2 : 1;
    for (int m = 0; m < nmat; ++m) {
        const float* W  = (m == 0) ? W1T : W2T;
        const float* hv = (m == 0) ? hin1 : hin2;
        for (int c = 0; c < 4; ++c) {           // K chunks of 256
            __syncthreads();                     // protect previous chunk reads
            #pragma unroll
            for (int j = 0; j < 4; ++j) {
                int i4 = tid + j * 512;          // 0..2047 float4s
                int f  = i4 << 2;                // 0..8191 floats  (b = f>>8, kc = f&255)
                int b  = f >> 8;
                int kc = f & 255;
                float4 v = *reinterpret_cast<const float4*>(&hv[b * HH + c * 256 + kc]);
                hs[kc + 0][b] = v.x;
                hs[kc + 1][b] = v.y;
                hs[kc + 2][b] = v.z;
                hs[kc + 3][b] = v.w;
            }
            __syncthreads();
            const float* Wp = &W[(c * 256 + ks * 16) * HG + j4];
            #pragma unroll
            for (int kk = 0; kk < 16; ++kk) {
                float4 w = *reinterpret_cast<const float4*>(Wp + kk * HG);
                float4 h = *reinterpret_cast<const float4*>(&hs[ks * 16 + kk][bb * 4]);
                acc[0]  += w.x * h.x; acc[1]  += w.x * h.y; acc[2]  += w.x * h.z; acc[3]  += w.x * h.w;
                acc[4]  += w.y * h.x; acc[5]  += w.y * h.y; acc[6]  += w.y * h.z; acc[7]  += w.y * h.w;
                acc[8]  += w.z * h.x; acc[9]  += w.z * h.y; acc[10] += w.z * h.z; acc[11] += w.z * h.w;
                acc[12] += w.w * h.x; acc[13] += w.w * h.y; acc[14] += w.w * h.z; acc[15] += w.w * h.w;
            }
        }
    }
    __syncthreads();
    float* red = &hs[0][0];           // 16*512 = 8192 floats needed; 9216 available
    #pragma unroll
    for (int q = 0; q < 4; ++q)
        #pragma unroll
        for (int i = 0; i < 4; ++i)
            red[ks * 512 + (lj * 4 + q) * 32 + (bb * 4 + i)] = acc[q * 4 + i];
    __syncthreads();
    // one thread per output (16 j' x 32 b = 512)
    int o = tid;
    float z = 0.f;
    #pragma unroll
    for (int p = 0; p < 16; ++p) z += red[p * 512 + o];
    int jhat = o >> 5, b = o & 31;
    int jp = jbase + jhat;
    if (L1) {
        z += bI[jp];
    } else {
        int tv = tgt[b * TT + t];
        z += E0[tv * HG + jp];
    }
    __syncthreads();
    red[o] = z;
    __syncthreads();
    if (tid < 128) {                  // 4 units x 32 batch cells
        int ul = tid >> 5;
        int b2 = tid & 31;
        float zi = red[(ul * 4 + 0) * 32 + b2];
        float zf = red[(ul * 4 + 1) * 32 + b2];
        float zg = red[(ul * 4 + 2) * 32 + b2];
        float zo = red[(ul * 4 + 3) * 32 + b2];
        int u = (blockIdx.x << 2) + ul;
        float cp = cio[b2 * HH + u];
        float ig = 1.f / (1.f + __expf(-zi));
        float fg = 1.f / (1.f + __expf(-zf));
        float og = 1.f / (1.f + __expf(-zo));
        float gv = tanhf(zg);
        float cn = fg * cp + ig * gv;
        float hn = og * tanhf(cn);
        cio[b2 * HH + u]  = cn;
        hout[b2 * HH + u] = hn;
        if (L1) h1all[(b2 * TT + t) * HH + u] = hn;
    }
}

extern "C" void kernel_launch(void* const* d_in, const int* in_sizes, int n_in,
                              void* d_out, int out_size, void* d_ws, size_t ws_size,
                              hipStream_t stream) {
    const int*   targets = (const int*)d_in[1];
    const float* h0_in   = (const float*)d_in[2];
    const float* c0_in   = (const float*)d_in[3];
    const float* h1_in   = (const float*)d_in[4];
    const float* c1_in   = (const float*)d_in[5];
    const float* emb     = (const float*)d_in[6];
    const float* W_ih0   = (const float*)d_in[7];
    const float* W_hh0   = (const float*)d_in[8];
    const float* b0      = (const float*)d_in[9];
    const float* W_ih1   = (const float*)d_in[10];
    const float* W_hh1   = (const float*)d_in[11];
    const float* b1      = (const float*)d_in[12];
    const float* W_out   = (const float*)d_in[13];
    const float* b_out   = (const float*)d_in[14];
    float* out = (float*)d_out;

    float* ws = (float*)d_ws;
    float* Wih0T = ws + 0 * 1048576;
    float* Whh0T = ws + 4 * 1048576;
    float* Wih1T = ws + 8 * 1048576;
    float* Whh1T = ws + 12 * 1048576;
    float* E0    = ws + 16 * 1048576;          // 1M floats
    float* b0i   = ws + 17 * 1048576;
    float* b1i   = b0i + 4096;
    float* h0A   = b1i + 4096;
    float* h0B   = h0A + BB * HH;
    float* h1A   = h0B + BB * HH;
    float* h1B   = h1A + BB * HH;
    float* c0    = h1B + BB * HH;
    float* c1    = c0 + BB * HH;
    float* h1all = c1 + BB * HH;               // 8M floats
    // total ~26.42M floats (~106 MB); assumes ws_size is sufficient.

    // 1) weight reorder (gate-interleaved) + bias interleave
    transpose_gates<<<4096, 256, 0, stream>>>(W_ih0, Wih0T);
    transpose_gates<<<4096, 256, 0, stream>>>(W_hh0, Whh0T);
    transpose_gates<<<4096, 256, 0, stream>>>(W_ih1, Wih1T);
    transpose_gates<<<4096, 256, 0, stream>>>(W_hh1, Whh1T);
    interleave_bias<<<16, 256, 0, stream>>>(b0, b1, b0i, b1i);

    // 2) init running states
    init_states<<<512, 256, 0, stream>>>(h0_in, c0_in, h1_in, c1_in, h0A, c0, h1A, c1);

    // 3) E0 = emb @ Wih0T + b0i   (M=256, N=4096, K=1024)
    gemm_bias<<<dim3(HG / 64, VV / 64), 256, 0, stream>>>(emb, Wih0T, b0i, E0, VV, HG, HH);

    // 4) sequential recurrence
    for (int t = 0; t < TT; ++t) {
        float* h0r = (t & 1) ? h0B : h0A;
        float* h0w = (t & 1) ? h0A : h0B;
        float* h1r = (t & 1) ? h1B : h1A;
        float* h1w = (t & 1) ? h1A : h1B;
        lstm_step<false><<<256, 512, 0, stream>>>(Whh0T, h0r, nullptr, nullptr,
                                                  E0, nullptr, targets, c0, h0w, nullptr, t);
        lstm_step<true><<<256, 512, 0, stream>>>(Wih1T, h0w, Whh1T, h1r,
                                                 nullptr, b1i, targets, c1, h1w, h1all, t);
    }
    // final h0 in h0A, h1 in h1A (256 steps: ...B->A)

    // 5) logits = h1all @ W_out + b_out   (M=8192, N=256, K=1024) -> d_out
    gemm_bias<<<dim3(VV / 64, (BB * TT) / 64), 256, 0, stream>>>(h1all, W_out, b_out, out,
                                                                 BB * TT, VV, HH);

    // 6) final states
    copy_finals<<<512, 256, 0, stream>>>(h0A, c0, h1A, c1, out + BB * TT * VV);
}

// Round 2
// 6706.508 us; speedup vs baseline: 2.2909x; 2.2909x over previous
//
#include <hip/hip_runtime.h>
#include <cstdint>

// CharRNN 2-layer LSTM, B=32,T=256,H=1024,V=256. Persistent-kernel design:
//   wgs 0..127  = layer-0 chain (owns 8 units each), Whh0 hi+lo frags in LDS
//   wgs 128..255= layer-1 chain (owns 8 units each), Wih1/Whh1 hi frags in LDS, lo streamed
//   h passed between CUs as bf16 hi/lo B-fragments; per-step flag sync (agent atomics)
//   math: mfma_f32_16x16x32_bf16 with split-bf16 (hi*hi + hi*lo + lo*hi) ~ f32 accuracy
//   E0 = emb@W_ih0+b0 computed per-CU at start (own 32 gate-cols only -> no sync)
//   logits = h1 frags @ W_out frags per-CU at end

typedef float  f32x4 __attribute__((ext_vector_type(4)));
typedef short  s16x8 __attribute__((ext_vector_type(8)));

#define DEV __device__ __forceinline__

DEV unsigned short f2bf(float x){
  unsigned u = __builtin_bit_cast(unsigned, x);
  unsigned r = (u + 0x7fffu + ((u >> 16) & 1u)) >> 16;   // round-nearest-even
  return (unsigned short)r;
}
DEV float bf2f(unsigned short b){ return __builtin_bit_cast(float, ((unsigned)b) << 16); }

DEV s16x8 ld16(const void* p){ return *(const s16x8*)p; }

DEV f32x4 MF(s16x8 a, s16x8 b, f32x4 c){
  return __builtin_amdgcn_mfma_f32_16x16x32_bf16(a, b, c, 0, 0, 0);
}

DEV void wait_ge(const int* p, int v){
  while (__hip_atomic_load(p, __ATOMIC_RELAXED, __HIP_MEMORY_SCOPE_AGENT) < v)
    __builtin_amdgcn_s_sleep(2);
}

// ---------------- prep: W[k][g*H+u] -> A-frag hi/lo bf16 [jb256][part2][ks32][64*16B] ----
__global__ void prep_wfrag(const float* __restrict__ W0, const float* __restrict__ W1,
                           const float* __restrict__ W2, const float* __restrict__ W3,
                           char* D0, char* D1, char* D2, char* D3) {
  int gid = blockIdx.x * 256 + threadIdx.x;       // 4*256*32*64 = 2M
  int lane = gid & 63, ks = (gid >> 6) & 31, jb = (gid >> 11) & 255, mat = gid >> 19;
  const float* S = (mat == 0) ? W0 : (mat == 1) ? W1 : (mat == 2) ? W2 : W3;
  char* D = (mat == 0) ? D0 : (mat == 1) ? D1 : (mat == 2) ? D2 : D3;
  int jp = jb * 16 + (lane & 15), u = jp >> 2, g = jp & 3;
  int kb = ks * 32 + (lane >> 4) * 8;
  s16x8 vh, vl;
  #pragma unroll
  for (int i = 0; i < 8; ++i) {
    float x = S[(kb + i) * 4096 + g * 1024 + u];
    unsigned short h = f2bf(x);
    vh[i] = (short)h;
    vl[i] = (short)f2bf(x - bf2f(h));
  }
  *(s16x8*)(D + (((jb * 2 + 0) * 32 + ks) << 10) + lane * 16) = vh;
  *(s16x8*)(D + (((jb * 2 + 1) * 32 + ks) << 10) + lane * 16) = vl;
}

// ---------------- prep: emb [v][k] and W_out [k][v] -> B-frag hi/lo [vb16][part2][ks32] ----
__global__ void prep_bfrag(const float* __restrict__ emb, const float* __restrict__ Wout,
                           char* Demb, char* Dwout) {
  int gid = blockIdx.x * 256 + threadIdx.x;       // 2*16*32*64 = 64K
  int lane = gid & 63, ks = (gid >> 6) & 31, vb = (gid >> 11) & 15, which = gid >> 15;
  int v = vb * 16 + (lane & 15), kb = ks * 32 + (lane >> 4) * 8;
  s16x8 vh, vl;
  #pragma unroll
  for (int i = 0; i < 8; ++i) {
    float x = which ? Wout[(kb + i) * 256 + v] : emb[v * 1024 + kb + i];
    unsigned short h = f2bf(x);
    vh[i] = (short)h;
    vl[i] = (short)f2bf(x - bf2f(h));
  }
  char* D = which ? Dwout : Demb;
  *(s16x8*)(D + (((vb * 2 + 0) * 32 + ks) << 10) + lane * 16) = vh;
  *(s16x8*)(D + (((vb * 2 + 1) * 32 + ks) << 10) + lane * 16) = vl;
}

// ---------------- prep: h0_in/h1_in [b][k] f32 -> h-frag slot0 [part2][nt2][ks32] ----
__global__ void prep_hinit(const float* __restrict__ h0, const float* __restrict__ h1,
                           char* ring, char* h1f) {
  int gid = blockIdx.x * 256 + threadIdx.x;       // 2*2*32*64 = 8192
  int lane = gid & 63, ks = (gid >> 6) & 31, nt = (gid >> 11) & 1, which = gid >> 12;
  const float* S = which ? h1 : h0;
  char* D = which ? h1f : ring;                   // slot 0 of each
  int b = nt * 16 + (lane & 15), kb = ks * 32 + (lane >> 4) * 8;
  s16x8 vh, vl;
  #pragma unroll
  for (int i = 0; i < 8; ++i) {
    float x = S[b * 1024 + kb + i];
    unsigned short h = f2bf(x);
    vh[i] = (short)h;
    vl[i] = (short)f2bf(x - bf2f(h));
  }
  *(s16x8*)(D + (((0 * 2 + nt) * 32 + ks) << 10) + lane * 16) = vh;
  *(s16x8*)(D + (((1 * 2 + nt) * 32 + ks) << 10) + lane * 16) = vl;
}

// ---------------- prep: zero flags (set [0]=128), gate-interleave b1 ----
__global__ void prep_misc(const float* __restrict__ b1, float* b1i, int* a0, int* a1) {
  int i = blockIdx.x * 256 + threadIdx.x;         // 4608
  if (i < 4096) b1i[i] = b1[(i & 3) * 1024 + (i >> 2)];
  if (i < 257) { a0[i] = (i == 0) ? 128 : 0; a1[i] = (i == 0) ? 128 : 0; }
}

// ---------------- the persistent LSTM kernel ----------------
__global__ __launch_bounds__(256, 1) void lstm_persist(
    const int* __restrict__ tgt,
    const float* __restrict__ c0_in, const float* __restrict__ c1_in,
    const float* __restrict__ b0, const float* __restrict__ b_out,
    const char* __restrict__ WA0, const char* __restrict__ WA1, const char* __restrict__ WA2,
    const char* __restrict__ WAi0, const char* __restrict__ WoutB, const char* __restrict__ embB,
    float* __restrict__ E0, const float* __restrict__ b1i,
    char* __restrict__ h0ring, char* __restrict__ h1frag,
    int* __restrict__ a0, int* __restrict__ a1,
    float* __restrict__ out)
{
  extern __shared__ char smem[];                  // 128KB A-frags + 12KB reduce scratch
  const int tid = threadIdx.x, lane = tid & 63, wv = tid >> 6;
  const int wg = blockIdx.x;
  const bool isL0 = (wg < 128);
  const int wgl = isL0 ? wg : (wg - 128);
  const int l15 = lane & 15, l4 = lane >> 4;

  // ---- stage A-frags into LDS: L0 = Whh0 hi+lo ; L1 = {Wih1,Whh1} hi ----
  if (isL0) {
    for (int idx = tid; idx < 8192; idx += 256) {
      int l16 = idx & 63, ks = (idx >> 6) & 31, mi = (idx >> 11) & 1, part = idx >> 12;
      uint4 v = *(const uint4*)(WA0 + ((((wgl * 2 + mi) * 2 + part) * 32 + ks) << 10) + l16 * 16);
      *(uint4*)(smem + (((part * 2 + mi) * 32 + ks) << 10) + l16 * 16) = v;
    }
  } else {
    for (int idx = tid; idx < 8192; idx += 256) {
      int l16 = idx & 63, ks = (idx >> 6) & 31, mi = (idx >> 11) & 1, mat = idx >> 12;
      const char* W = mat ? WA2 : WA1;
      uint4 v = *(const uint4*)(W + ((((wgl * 2 + mi) * 2 + 0) * 32 + ks) << 10) + l16 * 16);
      *(uint4*)(smem + (((mat * 2 + mi) * 32 + ks) << 10) + l16 * 16) = v;
    }
  }

  // ---- E0 = emb @ Wih0 + b0, own 32 gate-cols only (L0 wgs) ----
  if (isL0) {
    f32x4 C[2][4];
    #pragma unroll
    for (int a = 0; a < 2; ++a)
      #pragma unroll
      for (int b = 0; b < 4; ++b) C[a][b] = 0.0f;
    for (int ks = 0; ks < 32; ++ks) {
      s16x8 Ah[2], Al[2];
      #pragma unroll
      for (int mi = 0; mi < 2; ++mi) {
        Ah[mi] = ld16(WAi0 + ((((wgl * 2 + mi) * 2 + 0) * 32 + ks) << 10) + lane * 16);
        Al[mi] = ld16(WAi0 + ((((wgl * 2 + mi) * 2 + 1) * 32 + ks) << 10) + lane * 16);
      }
      #pragma unroll
      for (int v4 = 0; v4 < 4; ++v4) {
        int vb = wv * 4 + v4;
        s16x8 Bh = ld16(embB + (((vb * 2 + 0) * 32 + ks) << 10) + lane * 16);
        s16x8 Bl = ld16(embB + (((vb * 2 + 1) * 32 + ks) << 10) + lane * 16);
        #pragma unroll
        for (int mi = 0; mi < 2; ++mi) {
          C[mi][v4] = MF(Ah[mi], Bh, C[mi][v4]);
          C[mi][v4] = MF(Ah[mi], Bl, C[mi][v4]);
          C[mi][v4] = MF(Al[mi], Bh, C[mi][v4]);
        }
      }
    }
    #pragma unroll
    for (int mi = 0; mi < 2; ++mi) {
      int jb4 = wgl * 32 + mi * 16 + l4 * 4;      // 4 consecutive gate-cols
      int u = jb4 >> 2;
      f32x4 bb;
      #pragma unroll
      for (int r = 0; r < 4; ++r) bb[r] = b0[r * 1024 + u];
      #pragma unroll
      for (int v4 = 0; v4 < 4; ++v4) {
        int v = (wv * 4 + v4) * 16 + l15;
        *(f32x4*)(E0 + v * 4096 + jb4) = C[mi][v4] + bb;
      }
    }
  }

  // ---- c state into wave-0 registers ----
  float cst[2][2];
  if (wv == 0) {
    const float* cs = isL0 ? c0_in : c1_in;
    #pragma unroll
    for (int mi = 0; mi < 2; ++mi)
      #pragma unroll
      for (int nt = 0; nt < 2; ++nt)
        cst[mi][nt] = cs[(nt * 16 + l15) * 1024 + wgl * 8 + mi * 4 + l4];
  }
  __syncthreads();

  // ---- sequential recurrence ----
  for (int t = 0; t < 256; ++t) {
    const int s = t + 1;
    if (tid == 0) {
      if (isL0) {
        wait_ge(a0 + t, 128);                      // h0_{t-1} complete
        if (s >= 16) wait_ge(a1 + (s - 16), 128);  // ring slot recycled safely
      } else {
        wait_ge(a0 + s, 128);                      // h0_t ready
        wait_ge(a1 + t, 128);                      // h1_{t-1} complete
      }
      __threadfence();                             // acquire: inv L1/L2
    }
    __syncthreads();

    f32x4 C[2][2];
    #pragma unroll
    for (int a = 0; a < 2; ++a)
      #pragma unroll
      for (int b = 0; b < 2; ++b) C[a][b] = 0.0f;

    if (isL0) {
      const char* Bb = h0ring + (size_t)(t & 15) * 131072;
      for (int ks = wv * 8; ks < wv * 8 + 8; ++ks) {
        s16x8 Bh0 = ld16(Bb + (((0 * 2 + 0) * 32 + ks) << 10) + lane * 16);
        s16x8 Bh1 = ld16(Bb + (((0 * 2 + 1) * 32 + ks) << 10) + lane * 16);
        s16x8 Bl0 = ld16(Bb + (((1 * 2 + 0) * 32 + ks) << 10) + lane * 16);
        s16x8 Bl1 = ld16(Bb + (((1 * 2 + 1) * 32 + ks) << 10) + lane * 16);
        s16x8 Ah0 = ld16(smem + (((0 * 2 + 0) * 32 + ks) << 10) + lane * 16);
        s16x8 Ah1 = ld16(smem + (((0 * 2 + 1) * 32 + ks) << 10) + lane * 16);
        s16x8 Al0 = ld16(smem + (((1 * 2 + 0) * 32 + ks) << 10) + lane * 16);
        s16x8 Al1 = ld16(smem + (((1 * 2 + 1) * 32 + ks) << 10) + lane * 16);
        C[0][0] = MF(Ah0, Bh0, C[0][0]); C[0][0] = MF(Ah0, Bl0, C[0][0]); C[0][0] = MF(Al0, Bh0, C[0][0]);
        C[0][1] = MF(Ah0, Bh1, C[0][1]); C[0][1] = MF(Ah0, Bl1, C[0][1]); C[0][1] = MF(Al0, Bh1, C[0][1]);
        C[1][0] = MF(Ah1, Bh0, C[1][0]); C[1][0] = MF(Ah1, Bl0, C[1][0]); C[1][0] = MF(Al1, Bh0, C[1][0]);
        C[1][1] = MF(Ah1, Bh1, C[1][1]); C[1][1] = MF(Ah1, Bl1, C[1][1]); C[1][1] = MF(Al1, Bh1, C[1][1]);
      }
    } else {
      const char* B0 = h0ring + (size_t)(s & 15) * 131072;
      const char* B1 = h1frag + (size_t)t * 131072;
      for (int kq = wv * 16; kq < wv * 16 + 16; ++kq) {
        int mat = kq >> 5, ks = kq & 31;
        const char* Bb = mat ? B1 : B0;
        const char* WA = mat ? WA2 : WA1;
        s16x8 Bh0 = ld16(Bb + (((0 * 2 + 0) * 32 + ks) << 10) + lane * 16);
        s16x8 Bh1 = ld16(Bb + (((0 * 2 + 1) * 32 + ks) << 10) + lane * 16);
        s16x8 Bl0 = ld16(Bb + (((1 * 2 + 0) * 32 + ks) << 10) + lane * 16);
        s16x8 Bl1 = ld16(Bb + (((1 * 2 + 1) * 32 + ks) << 10) + lane * 16);
        s16x8 Ah0 = ld16(smem + (((mat * 2 + 0) * 32 + ks) << 10) + lane * 16);
        s16x8 Ah1 = ld16(smem + (((mat * 2 + 1) * 32 + ks) << 10) + lane * 16);
        s16x8 Al0 = ld16(WA + ((((wgl * 2 + 0) * 2 + 1) * 32 + ks) << 10) + lane * 16);
        s16x8 Al1 = ld16(WA + ((((wgl * 2 + 1) * 2 + 1) * 32 + ks) << 10) + lane * 16);
        C[0][0] = MF(Ah0, Bh0, C[0][0]); C[0][0] = MF(Ah0, Bl0, C[0][0]); C[0][0] = MF(Al0, Bh0, C[0][0]);
        C[0][1] = MF(Ah0, Bh1, C[0][1]); C[0][1] = MF(Ah0, Bl1, C[0][1]); C[0][1] = MF(Al0, Bh1, C[0][1]);
        C[1][0] = MF(Ah1, Bh0, C[1][0]); C[1][0] = MF(Ah1, Bl0, C[1][0]); C[1][0] = MF(Al1, Bh0, C[1][0]);
        C[1][1] = MF(Ah1, Bh1, C[1][1]); C[1][1] = MF(Ah1, Bl1, C[1][1]); C[1][1] = MF(Al1, Bh1, C[1][1]);
      }
    }

    if (wv) {
      #pragma unroll
      for (int mi = 0; mi < 2; ++mi)
        #pragma unroll
        for (int nt = 0; nt < 2; ++nt)
          *(f32x4*)(smem + 131072 + ((wv - 1) * 4 + mi * 2 + nt) * 1024 + lane * 16) = C[mi][nt];
    }
    __syncthreads();

    if (wv == 0) {
      char* hd = isL0 ? (h0ring + (size_t)(s & 15) * 131072)
                      : (h1frag + (size_t)s * 131072);
      #pragma unroll
      for (int mi = 0; mi < 2; ++mi) {
        #pragma unroll
        for (int nt = 0; nt < 2; ++nt) {
          f32x4 z = C[mi][nt];
          #pragma unroll
          for (int w = 1; w < 4; ++w)
            z += *(const f32x4*)(smem + 131072 + ((w - 1) * 4 + mi * 2 + nt) * 1024 + lane * 16);
          if (isL0) {
            int tv = tgt[(nt * 16 + l15) * 256 + t];
            z += *(const f32x4*)(E0 + tv * 4096 + wgl * 32 + mi * 16 + l4 * 4);
          } else {
            z += *(const f32x4*)(b1i + wgl * 32 + mi * 16 + l4 * 4);
          }
          float ig = 1.f / (1.f + __expf(-z[0]));
          float fg = 1.f / (1.f + __expf(-z[1]));
          float og = 1.f / (1.f + __expf(-z[3]));
          float cn = fg * cst[mi][nt] + ig * tanhf(z[2]);
          float hn = og * tanhf(cn);
          cst[mi][nt] = cn;
          unsigned short hb = f2bf(hn);
          unsigned short lb = f2bf(hn - bf2f(hb));
          int base = ((0 * 2 + nt) * 32 + (wgl >> 2)) * 1024 + ((wgl & 3) * 16 + l15) * 16 + (mi * 4 + l4) * 2;
          *(unsigned short*)(hd + base) = hb;
          *(unsigned short*)(hd + base + 65536) = lb;
          if (t == 255) {
            int u = wgl * 8 + mi * 4 + l4, b = nt * 16 + l15;
            int off = isL0 ? 0 : 65536;
            out[2097152 + off + b * 1024 + u] = hn;
            out[2097152 + off + 32768 + b * 1024 + u] = cn;
          }
        }
      }
      __threadfence();                             // release: drain + writeback
      if (lane == 0)
        __hip_atomic_fetch_add(isL0 ? (a0 + s) : (a1 + s), 1,
                               __ATOMIC_RELAXED, __HIP_MEMORY_SCOPE_AGENT);
    }
  }

  // ---- projection: logits[b][t][v] = h1_t @ W_out + b_out ; one t per CU ----
  {
    const int t = isL0 ? (128 + wgl) : wgl;        // L1 wgs take early t's (already done)
    if (tid == 0) { wait_ge(a1 + t + 1, 128); __threadfence(); }
    __syncthreads();
    const char* A = h1frag + (size_t)(t + 1) * 131072;
    f32x4 C[2][4];
    #pragma unroll
    for (int a = 0; a < 2; ++a)
      #pragma unroll
      for (int b = 0; b < 4; ++b) C[a][b] = 0.0f;
    for (int ks = 0; ks < 32; ++ks) {
      s16x8 Ah0 = ld16(A + (((0 * 2 + 0) * 32 + ks) << 10) + lane * 16);
      s16x8 Ah1 = ld16(A + (((0 * 2 + 1) * 32 + ks) << 10) + lane * 16);
      s16x8 Al0 = ld16(A + (((1 * 2 + 0) * 32 + ks) << 10) + lane * 16);
      s16x8 Al1 = ld16(A + (((1 * 2 + 1) * 32 + ks) << 10) + lane * 16);
      #pragma unroll
      for (int v4 = 0; v4 < 4; ++v4) {
        int vb = wv * 4 + v4;
        s16x8 Bh = ld16(WoutB + (((vb * 2 + 0) * 32 + ks) << 10) + lane * 16);
        s16x8 Bl = ld16(WoutB + (((vb * 2 + 1) * 32 + ks) << 10) + lane * 16);
        C[0][v4] = MF(Ah0, Bh, C[0][v4]); C[0][v4] = MF(Ah0, Bl, C[0][v4]); C[0][v4] = MF(Al0, Bh, C[0][v4]);
        C[1][v4] = MF(Ah1, Bh, C[1][v4]); C[1][v4] = MF(Ah1, Bl, C[1][v4]); C[1][v4] = MF(Al1, Bh, C[1][v4]);
      }
    }
    #pragma unroll
    for (int nt = 0; nt < 2; ++nt)
      #pragma unroll
      for (int v4 = 0; v4 < 4; ++v4) {
        int v = (wv * 4 + v4) * 16 + l15;
        float bo = b_out[v];
        #pragma unroll
        for (int r = 0; r < 4; ++r) {
          int b = nt * 16 + l4 * 4 + r;
          out[((size_t)b * 256 + t) * 256 + v] = C[nt][v4][r] + bo;
        }
      }
  }
}

extern "C" void kernel_launch(void* const* d_in, const int* in_sizes, int n_in,
                              void* d_out, int out_size, void* d_ws, size_t ws_size,
                              hipStream_t stream) {
  const int*   targets = (const int*)d_in[1];
  const float* h0_in   = (const float*)d_in[2];
  const float* c0_in   = (const float*)d_in[3];
  const float* h1_in   = (const float*)d_in[4];
  const float* c1_in   = (const float*)d_in[5];
  const float* emb     = (const float*)d_in[6];
  const float* W_ih0   = (const float*)d_in[7];
  const float* W_hh0   = (const float*)d_in[8];
  const float* b0      = (const float*)d_in[9];
  const float* W_ih1   = (const float*)d_in[10];
  const float* W_hh1   = (const float*)d_in[11];
  const float* b1      = (const float*)d_in[12];
  const float* W_out   = (const float*)d_in[13];
  const float* b_out   = (const float*)d_in[14];
  float* out = (float*)d_out;

  char* ws = (char*)d_ws;
  char*  WA0    = ws;                         // Whh0 A-frags hi/lo, 16MB
  char*  WA1    = ws + 16777216;              // Wih1
  char*  WA2    = ws + 33554432;              // Whh1
  char*  WoutB  = ws + 50331648;              // W_out B-frags, 1MB
  char*  embB   = ws + 51380224;              // emb B-frags, 1MB
  float* E0     = (float*)(ws + 52428800);    // 4MB f32
  float* b1i    = (float*)(ws + 56623104);    // 16KB
  int*   a0     = (int*)(ws + 56639488);      // flags, 4KB
  int*   a1     = (int*)(ws + 56643584);
  char*  h0ring = ws + 56647680;              // 16 slots x 128KB
  char*  h1frag = ws + 58744832;              // 257 slots x 128KB
  char*  WAi0   = h1frag + 16777216;          // Wih0 A-frags, aliased into h1frag slots 128+
                                              // (consumed for E0 within ~10us; slot 128 written at step 127)

  prep_misc <<<18,   256, 0, stream>>>(b1, b1i, a0, a1);
  prep_wfrag<<<8192, 256, 0, stream>>>(W_hh0, W_ih1, W_hh1, W_ih0, WA0, WA1, WA2, WAi0);
  prep_bfrag<<<256,  256, 0, stream>>>(emb, W_out, embB, WoutB);
  prep_hinit<<<32,   256, 0, stream>>>(h0_in, h1_in, h0ring, h1frag);

  hipFuncSetAttribute(reinterpret_cast<const void*>(lstm_persist),
                      hipFuncAttributeMaxDynamicSharedMemorySize, 143360);
  lstm_persist<<<256, 256, 143360, stream>>>(
      targets, c0_in, c1_in, b0, b_out,
      WA0, WA1, WA2, WAi0, WoutB, embB,
      E0, b1i, h0ring, h1frag, a0, a1, out);
}

// Round 3
// 2348.446 us; speedup vs baseline: 6.5421x; 2.8557x over previous
//
#include <hip/hip_runtime.h>
#include <cstdint>

// CharRNN 2-layer LSTM, B=32,T=256,H=1024,V=256. Persistent-kernel design (round 3):
//   wgs 0..127  = layer-0 chain (8 units each), Whh0 hi+lo frags in LDS
//   wgs 128..255= layer-1 chain (8 units each), Wih1/Whh1 hi frags in LDS, lo streamed from L2
//   sync: per-wg flag words (relaxed agent atomics) + explicit sc0/sc1 coherent h traffic.
//   NO __threadfence (no L2 writeback/invalidate): producer = sc0sc1 stores + vmcnt(0) + flag;
//   consumer = poll flags + sc0sc1 loads (bypass stale L1/L2). Weights stay L2-resident.
//   math: mfma_f32_16x16x32_bf16 split-bf16 (hi*hi + hi*lo + lo*hi) ~ f32 accuracy.

typedef float  f32x4 __attribute__((ext_vector_type(4)));
typedef short  s16x8 __attribute__((ext_vector_type(8)));

#define DEV __device__ __forceinline__

DEV unsigned short f2bf(float x){
  unsigned u = __builtin_bit_cast(unsigned, x);
  unsigned r = (u + 0x7fffu + ((u >> 16) & 1u)) >> 16;   // round-nearest-even
  return (unsigned short)r;
}
DEV float bf2f(unsigned short b){ return __builtin_bit_cast(float, ((unsigned)b) << 16); }

DEV s16x8 ld16(const void* p){ return *(const s16x8*)p; }

DEV f32x4 MF(s16x8 a, s16x8 b, f32x4 c){
  return __builtin_amdgcn_mfma_f32_16x16x32_bf16(a, b, c, 0, 0, 0);
}

// coherent (device-scope) 16B load: bypass L1+L2, read from coherence point
#define LDC(dst, ptr)  asm volatile("global_load_dwordx4 %0, %1, off sc0 sc1" : "=v"(dst) : "v"(ptr))
// plain 16B load via asm (participates in OUR vmcnt accounting, L2-cacheable)
#define LDP(dst, ptr)  asm volatile("global_load_dwordx4 %0, %1, off"         : "=v"(dst) : "v"(ptr))
#define WAITVM(n) do { asm volatile("s_waitcnt vmcnt(" #n ")" ::: "memory"); \
                       __builtin_amdgcn_sched_barrier(0); } while (0)
#define TRIPLE(Cmn, Ahm, Alm, Bhn, Bln) do { \
    Cmn = MF(Ahm, Bhn, Cmn); Cmn = MF(Ahm, Bln, Cmn); Cmn = MF(Alm, Bhn, Cmn); } while (0)

DEV void st2c(void* p, unsigned short v){   // coherent 2B store
  asm volatile("global_store_short %0, %1, off sc0 sc1" :: "v"(p), "v"((unsigned)v) : "memory");
}
DEV void set_flag(int* p, int v){
  __hip_atomic_store(p, v, __ATOMIC_RELAXED, __HIP_MEMORY_SCOPE_AGENT);
}
// wave-0 collective poll: all 128 flags (stride 8 ints) >= target
DEV void poll2(const int* f, int lane, int target){
  const int* p0 = f + lane * 8;
  const int* p1 = f + (64 + lane) * 8;
  for (;;) {
    int a = __hip_atomic_load(p0, __ATOMIC_RELAXED, __HIP_MEMORY_SCOPE_AGENT);
    int b = __hip_atomic_load(p1, __ATOMIC_RELAXED, __HIP_MEMORY_SCOPE_AGENT);
    if (__all((a >= target) && (b >= target))) break;
    __builtin_amdgcn_s_sleep(4);
  }
}

// ---------------- prep: W[k][g*H+u] -> A-frag hi/lo bf16 [jb256][part2][ks32][64*16B] ----
__global__ void prep_wfrag(const float* __restrict__ W0, const float* __restrict__ W1,
                           const float* __restrict__ W2, const float* __restrict__ W3,
                           char* D0, char* D1, char* D2, char* D3) {
  int gid = blockIdx.x * 256 + threadIdx.x;       // 4*256*32*64 = 2M
  int lane = gid & 63, ks = (gid >> 6) & 31, jb = (gid >> 11) & 255, mat = gid >> 19;
  const float* S = (mat == 0) ? W0 : (mat == 1) ? W1 : (mat == 2) ? W2 : W3;
  char* D = (mat == 0) ? D0 : (mat == 1) ? D1 : (mat == 2) ? D2 : D3;
  int jp = jb * 16 + (lane & 15), u = jp >> 2, g = jp & 3;
  int kb = ks * 32 + (lane >> 4) * 8;
  s16x8 vh, vl;
  #pragma unroll
  for (int i = 0; i < 8; ++i) {
    float x = S[(kb + i) * 4096 + g * 1024 + u];
    unsigned short h = f2bf(x);
    vh[i] = (short)h;
    vl[i] = (short)f2bf(x - bf2f(h));
  }
  *(s16x8*)(D + (((jb * 2 + 0) * 32 + ks) << 10) + lane * 16) = vh;
  *(s16x8*)(D + (((jb * 2 + 1) * 32 + ks) << 10) + lane * 16) = vl;
}

// ---------------- prep: emb [v][k] and W_out [k][v] -> B-frag hi/lo [vb16][part2][ks32] ----
__global__ void prep_bfrag(const float* __restrict__ emb, const float* __restrict__ Wout,
                           char* Demb, char* Dwout) {
  int gid = blockIdx.x * 256 + threadIdx.x;       // 2*16*32*64 = 64K
  int lane = gid & 63, ks = (gid >> 6) & 31, vb = (gid >> 11) & 15, which = gid >> 15;
  int v = vb * 16 + (lane & 15), kb = ks * 32 + (lane >> 4) * 8;
  s16x8 vh, vl;
  #pragma unroll
  for (int i = 0; i < 8; ++i) {
    float x = which ? Wout[(kb + i) * 256 + v] : emb[v * 1024 + kb + i];
    unsigned short h = f2bf(x);
    vh[i] = (short)h;
    vl[i] = (short)f2bf(x - bf2f(h));
  }
  char* D = which ? Dwout : Demb;
  *(s16x8*)(D + (((vb * 2 + 0) * 32 + ks) << 10) + lane * 16) = vh;
  *(s16x8*)(D + (((vb * 2 + 1) * 32 + ks) << 10) + lane * 16) = vl;
}

// ---------------- prep: h0_in/h1_in [b][k] f32 -> h-frag slot0 [part2][nt2][ks32] ----
__global__ void prep_hinit(const float* __restrict__ h0, const float* __restrict__ h1,
                           char* ring, char* h1f) {
  int gid = blockIdx.x * 256 + threadIdx.x;       // 2*2*32*64 = 8192
  int lane = gid & 63, ks = (gid >> 6) & 31, nt = (gid >> 11) & 1, which = gid >> 12;
  const float* S = which ? h1 : h0;
  char* D = which ? h1f : ring;                   // slot 0 of each
  int b = nt * 16 + (lane & 15), kb = ks * 32 + (lane >> 4) * 8;
  s16x8 vh, vl;
  #pragma unroll
  for (int i = 0; i < 8; ++i) {
    float x = S[b * 1024 + kb + i];
    unsigned short h = f2bf(x);
    vh[i] = (short)h;
    vl[i] = (short)f2bf(x - bf2f(h));
  }
  *(s16x8*)(D + (((0 * 2 + nt) * 32 + ks) << 10) + lane * 16) = vh;
  *(s16x8*)(D + (((1 * 2 + nt) * 32 + ks) << 10) + lane * 16) = vl;
}

// ---------------- prep: zero flag arrays, gate-interleave b1 ----
__global__ void prep_misc(const float* __restrict__ b1, float* b1i, int* f0a, int* f1a) {
  int i = blockIdx.x * 256 + threadIdx.x;         // 4608
  if (i < 4096) b1i[i] = b1[(i & 3) * 1024 + (i >> 2)];
  if (i < 1024) { f0a[i] = 0; f1a[i] = 0; }
}

// ---------------- the persistent LSTM kernel ----------------
__global__ __launch_bounds__(256, 1) void lstm_persist(
    const int* __restrict__ tgt,
    const float* __restrict__ c0_in, const float* __restrict__ c1_in,
    const float* __restrict__ b0, const float* __restrict__ b_out,
    const char* __restrict__ WA0, const char* __restrict__ WA1, const char* __restrict__ WA2,
    const char* __restrict__ WAi0, const char* __restrict__ WoutB, const char* __restrict__ embB,
    float* __restrict__ E0, const float* __restrict__ b1i,
    char* __restrict__ h0ring, char* __restrict__ h1frag,
    int* __restrict__ f0, int* __restrict__ f1,
    float* __restrict__ out)
{
  extern __shared__ char smem[];                  // 128KB A-frags + 12KB reduce scratch
  const int tid = threadIdx.x, lane = tid & 63, wv = tid >> 6;
  const int wg = blockIdx.x;
  const bool isL0 = (wg < 128);
  const int wgl = isL0 ? wg : (wg - 128);
  const int l15 = lane & 15, l4 = lane >> 4;

  // ---- stage A-frags into LDS: L0 = Whh0 hi+lo ; L1 = {Wih1,Whh1} hi ----
  if (isL0) {
    for (int idx = tid; idx < 8192; idx += 256) {
      int l16 = idx & 63, ks = (idx >> 6) & 31, mi = (idx >> 11) & 1, part = idx >> 12;
      uint4 v = *(const uint4*)(WA0 + ((((wgl * 2 + mi) * 2 + part) * 32 + ks) << 10) + l16 * 16);
      *(uint4*)(smem + (((part * 2 + mi) * 32 + ks) << 10) + l16 * 16) = v;
    }
  } else {
    for (int idx = tid; idx < 8192; idx += 256) {
      int l16 = idx & 63, ks = (idx >> 6) & 31, mi = (idx >> 11) & 1, mat = idx >> 12;
      const char* W = mat ? WA2 : WA1;
      uint4 v = *(const uint4*)(W + ((((wgl * 2 + mi) * 2 + 0) * 32 + ks) << 10) + l16 * 16);
      *(uint4*)(smem + (((mat * 2 + mi) * 32 + ks) << 10) + l16 * 16) = v;
    }
  }

  // ---- E0 = emb @ Wih0 + b0, own 32 gate-cols only (L0 wgs) ----
  if (isL0) {
    f32x4 C[2][4];
    #pragma unroll
    for (int a = 0; a < 2; ++a)
      #pragma unroll
      for (int b = 0; b < 4; ++b) C[a][b] = 0.0f;
    for (int ks = 0; ks < 32; ++ks) {
      s16x8 Ah[2], Al[2];
      #pragma unroll
      for (int mi = 0; mi < 2; ++mi) {
        Ah[mi] = ld16(WAi0 + ((((wgl * 2 + mi) * 2 + 0) * 32 + ks) << 10) + lane * 16);
        Al[mi] = ld16(WAi0 + ((((wgl * 2 + mi) * 2 + 1) * 32 + ks) << 10) + lane * 16);
      }
      #pragma unroll
      for (int v4 = 0; v4 < 4; ++v4) {
        int vb = wv * 4 + v4;
        s16x8 Bh = ld16(embB + (((vb * 2 + 0) * 32 + ks) << 10) + lane * 16);
        s16x8 Bl = ld16(embB + (((vb * 2 + 1) * 32 + ks) << 10) + lane * 16);
        #pragma unroll
        for (int mi = 0; mi < 2; ++mi) {
          C[mi][v4] = MF(Ah[mi], Bh, C[mi][v4]);
          C[mi][v4] = MF(Ah[mi], Bl, C[mi][v4]);
          C[mi][v4] = MF(Al[mi], Bh, C[mi][v4]);
        }
      }
    }
    #pragma unroll
    for (int mi = 0; mi < 2; ++mi) {
      int jb4 = wgl * 32 + mi * 16 + l4 * 4;      // 4 consecutive gate-cols
      int u = jb4 >> 2;
      f32x4 bb;
      #pragma unroll
      for (int r = 0; r < 4; ++r) bb[r] = b0[r * 1024 + u];
      #pragma unroll
      for (int v4 = 0; v4 < 4; ++v4) {
        int v = (wv * 4 + v4) * 16 + l15;
        *(f32x4*)(E0 + v * 4096 + jb4) = C[mi][v4] + bb;
      }
    }
  }

  // ---- c state into wave-0 registers ----
  float cst[2][2];
  if (wv == 0) {
    const float* cs = isL0 ? c0_in : c1_in;
    #pragma unroll
    for (int mi = 0; mi < 2; ++mi)
      #pragma unroll
      for (int nt = 0; nt < 2; ++nt)
        cst[mi][nt] = cs[(nt * 16 + l15) * 1024 + wgl * 8 + mi * 4 + l4];
  }
  __syncthreads();

  // ---- sequential recurrence ----
  for (int t = 0; t < 256; ++t) {
    const int s = t + 1;
    f32x4 C[2][2];
    #pragma unroll
    for (int a = 0; a < 2; ++a)
      #pragma unroll
      for (int b = 0; b < 2; ++b) C[a][b] = 0.0f;

    if (isL0) {
      if (wv == 0) {
        poll2(f0, lane, t);                        // all L0 wgs done step t-1
        if (s >= 16) poll2(f1, lane, s - 16);      // ring slot recycled safely
      }
      __syncthreads();
      const char* Bb = h0ring + (size_t)(t & 15) * 131072;
      const int ksb = wv * 8;
      s16x8 P[2][4];
      #pragma unroll
      for (int q = 0; q < 4; ++q) LDC(P[0][q], Bb + ((q * 32 + ksb) << 10) + lane * 16);
      #pragma unroll
      for (int i = 0; i < 8; ++i) {
        const int ks = ksb + i;
        if (i < 7) {
          #pragma unroll
          for (int q = 0; q < 4; ++q) LDC(P[(i + 1) & 1][q], Bb + ((q * 32 + ks + 1) << 10) + lane * 16);
        }
        s16x8 Ah0 = ld16(smem + ((0 * 32 + ks) << 10) + lane * 16);
        s16x8 Ah1 = ld16(smem + ((1 * 32 + ks) << 10) + lane * 16);
        s16x8 Al0 = ld16(smem + ((2 * 32 + ks) << 10) + lane * 16);
        s16x8 Al1 = ld16(smem + ((3 * 32 + ks) << 10) + lane * 16);
        if (i < 7) { WAITVM(4); } else { WAITVM(0); }
        TRIPLE(C[0][0], Ah0, Al0, P[i & 1][0], P[i & 1][2]);
        TRIPLE(C[0][1], Ah0, Al0, P[i & 1][1], P[i & 1][3]);
        TRIPLE(C[1][0], Ah1, Al1, P[i & 1][0], P[i & 1][2]);
        TRIPLE(C[1][1], Ah1, Al1, P[i & 1][1], P[i & 1][3]);
      }
    } else {
      // ---- half 1: own-layer h1_{t-1} (ready at f1>=t); hides L0's step t ----
      if (wv == 0) poll2(f1, lane, t);
      __syncthreads();
      {
        const char* Bb = h1frag + (size_t)t * 131072;
        const int ksb = wv * 8;
        s16x8 P[2][4], AL[2][2];
        #pragma unroll
        for (int q = 0; q < 4; ++q) LDC(P[0][q], Bb + ((q * 32 + ksb) << 10) + lane * 16);
        LDP(AL[0][0], WA2 + ((((wgl * 2 + 0) * 2 + 1) * 32 + ksb) << 10) + lane * 16);
        LDP(AL[0][1], WA2 + ((((wgl * 2 + 1) * 2 + 1) * 32 + ksb) << 10) + lane * 16);
        #pragma unroll
        for (int i = 0; i < 8; ++i) {
          const int ks = ksb + i;
          if (i < 7) {
            #pragma unroll
            for (int q = 0; q < 4; ++q) LDC(P[(i + 1) & 1][q], Bb + ((q * 32 + ks + 1) << 10) + lane * 16);
            LDP(AL[(i + 1) & 1][0], WA2 + ((((wgl * 2 + 0) * 2 + 1) * 32 + ks + 1) << 10) + lane * 16);
            LDP(AL[(i + 1) & 1][1], WA2 + ((((wgl * 2 + 1) * 2 + 1) * 32 + ks + 1) << 10) + lane * 16);
          }
          s16x8 Ah0 = ld16(smem + (((2 + 0) * 32 + ks) << 10) + lane * 16);
          s16x8 Ah1 = ld16(smem + (((2 + 1) * 32 + ks) << 10) + lane * 16);
          if (i < 7) { WAITVM(6); } else { WAITVM(0); }
          TRIPLE(C[0][0], Ah0, AL[i & 1][0], P[i & 1][0], P[i & 1][2]);
          TRIPLE(C[0][1], Ah0, AL[i & 1][0], P[i & 1][1], P[i & 1][3]);
          TRIPLE(C[1][0], Ah1, AL[i & 1][1], P[i & 1][0], P[i & 1][2]);
          TRIPLE(C[1][1], Ah1, AL[i & 1][1], P[i & 1][1], P[i & 1][3]);
        }
      }
      // ---- half 0: h0_t from layer 0 (f0>=s) ----
      if (wv == 0) poll2(f0, lane, s);
      __syncthreads();
      {
        const char* Bb = h0ring + (size_t)(s & 15) * 131072;
        const int ksb = wv * 8;
        s16x8 P[2][4], AL[2][2];
        #pragma unroll
        for (int q = 0; q < 4; ++q) LDC(P[0][q], Bb + ((q * 32 + ksb) << 10) + lane * 16);
        LDP(AL[0][0], WA1 + ((((wgl * 2 + 0) * 2 + 1) * 32 + ksb) << 10) + lane * 16);
        LDP(AL[0][1], WA1 + ((((wgl * 2 + 1) * 2 + 1) * 32 + ksb) << 10) + lane * 16);
        #pragma unroll
        for (int i = 0; i < 8; ++i) {
          const int ks = ksb + i;
          if (i < 7) {
            #pragma unroll
            for (int q = 0; q < 4; ++q) LDC(P[(i + 1) & 1][q], Bb + ((q * 32 + ks + 1) << 10) + lane * 16);
            LDP(AL[(i + 1) & 1][0], WA1 + ((((wgl * 2 + 0) * 2 + 1) * 32 + ks + 1) << 10) + lane * 16);
            LDP(AL[(i + 1) & 1][1], WA1 + ((((wgl * 2 + 1) * 2 + 1) * 32 + ks + 1) << 10) + lane * 16);
          }
          s16x8 Ah0 = ld16(smem + (((0 + 0) * 32 + ks) << 10) + lane * 16);
          s16x8 Ah1 = ld16(smem + (((0 + 1) * 32 + ks) << 10) + lane * 16);
          if (i < 7) { WAITVM(6); } else { WAITVM(0); }
          TRIPLE(C[0][0], Ah0, AL[i & 1][0], P[i & 1][0], P[i & 1][2]);
          TRIPLE(C[0][1], Ah0, AL[i & 1][0], P[i & 1][1], P[i & 1][3]);
          TRIPLE(C[1][0], Ah1, AL[i & 1][1], P[i & 1][0], P[i & 1][2]);
          TRIPLE(C[1][1], Ah1, AL[i & 1][1], P[i & 1][1], P[i & 1][3]);
        }
      }
    }

    if (wv) {
      #pragma unroll
      for (int mi = 0; mi < 2; ++mi)
        #pragma unroll
        for (int nt = 0; nt < 2; ++nt)
          *(f32x4*)(smem + 131072 + ((wv - 1) * 4 + mi * 2 + nt) * 1024 + lane * 16) = C[mi][nt];
    }
    __syncthreads();

    if (wv == 0) {
      char* hd = isL0 ? (h0ring + (size_t)(s & 15) * 131072)
                      : (h1frag + (size_t)s * 131072);
      #pragma unroll
      for (int mi = 0; mi < 2; ++mi) {
        #pragma unroll
        for (int nt = 0; nt < 2; ++nt) {
          f32x4 z = C[mi][nt];
          #pragma unroll
          for (int w = 1; w < 4; ++w)
            z += *(const f32x4*)(smem + 131072 + ((w - 1) * 4 + mi * 2 + nt) * 1024 + lane * 16);
          if (isL0) {
            int tv = tgt[(nt * 16 + l15) * 256 + t];
            z += *(const f32x4*)(E0 + tv * 4096 + wgl * 32 + mi * 16 + l4 * 4);
          } else {
            z += *(const f32x4*)(b1i + wgl * 32 + mi * 16 + l4 * 4);
          }
          float ig = 1.f / (1.f + __expf(-z[0]));
          float fg = 1.f / (1.f + __expf(-z[1]));
          float og = 1.f / (1.f + __expf(-z[3]));
          float cn = fg * cst[mi][nt] + ig * tanhf(z[2]);
          float hn = og * tanhf(cn);
          cst[mi][nt] = cn;
          unsigned short hb = f2bf(hn);
          unsigned short lb = f2bf(hn - bf2f(hb));
          int base = ((0 * 2 + nt) * 32 + (wgl >> 2)) * 1024 + ((wgl & 3) * 16 + l15) * 16 + (mi * 4 + l4) * 2;
          st2c(hd + base, hb);
          st2c(hd + base + 65536, lb);
          if (t == 255) {
            int u = wgl * 8 + mi * 4 + l4, b = nt * 16 + l15;
            int off = isL0 ? 0 : 65536;
            out[2097152 + off + b * 1024 + u] = hn;
            out[2097152 + off + 32768 + b * 1024 + u] = cn;
          }
        }
      }
      asm volatile("s_waitcnt vmcnt(0)" ::: "memory");   // h stores at coherence point
      if (lane == 0) set_flag((isL0 ? f0 : f1) + wgl * 8, s);
    }
  }

  // ---- projection: logits[b][t][v] = h1_t @ W_out + b_out ; one t per CU ----
  {
    const int tp = isL0 ? (128 + wgl) : wgl;       // L1 wgs take early t's (already done)
    if (wv == 0) poll2(f1, lane, tp + 1);
    __syncthreads();
    const char* A = h1frag + (size_t)(tp + 1) * 131072;
    f32x4 C[2][4];
    #pragma unroll
    for (int a = 0; a < 2; ++a)
      #pragma unroll
      for (int b = 0; b < 4; ++b) C[a][b] = 0.0f;
    s16x8 QA[4], QB[4];
    #pragma unroll
    for (int q = 0; q < 4; ++q) LDC(QA[q], A + ((q * 32 + 0) << 10) + lane * 16);
    for (int kk = 0; kk < 16; ++kk) {
      const int ks = kk * 2;
      #pragma unroll
      for (int q = 0; q < 4; ++q) LDC(QB[q], A + ((q * 32 + ks + 1) << 10) + lane * 16);
      asm volatile("s_waitcnt vmcnt(4)" ::: "memory");
      __builtin_amdgcn_sched_barrier(0);
      #pragma unroll
      for (int v4 = 0; v4 < 4; ++v4) {
        int vb = wv * 4 + v4;
        s16x8 Bh = ld16(WoutB + (((vb * 2 + 0) * 32 + ks) << 10) + lane * 16);
        s16x8 Bl = ld16(WoutB + (((vb * 2 + 1) * 32 + ks) << 10) + lane * 16);
        C[0][v4] = MF(QA[0], Bh, C[0][v4]); C[0][v4] = MF(QA[0], Bl, C[0][v4]); C[0][v4] = MF(QA[2], Bh, C[0][v4]);
        C[1][v4] = MF(QA[1], Bh, C[1][v4]); C[1][v4] = MF(QA[1], Bl, C[1][v4]); C[1][v4] = MF(QA[3], Bh, C[1][v4]);
      }
      if (kk < 15) {
        #pragma unroll
        for (int q = 0; q < 4; ++q) LDC(QA[q], A + ((q * 32 + ks + 2) << 10) + lane * 16);
        asm volatile("s_waitcnt vmcnt(4)" ::: "memory");
      } else {
        asm volatile("s_waitcnt vmcnt(0)" ::: "memory");
      }
      __builtin_amdgcn_sched_barrier(0);
      #pragma unroll
      for (int v4 = 0; v4 < 4; ++v4) {
        int vb = wv * 4 + v4;
        s16x8 Bh = ld16(WoutB + (((vb * 2 + 0) * 32 + ks + 1) << 10) + lane * 16);
        s16x8 Bl = ld16(WoutB + (((vb * 2 + 1) * 32 + ks + 1) << 10) + lane * 16);
        C[0][v4] = MF(QB[0], Bh, C[0][v4]); C[0][v4] = MF(QB[0], Bl, C[0][v4]); C[0][v4] = MF(QB[2], Bh, C[0][v4]);
        C[1][v4] = MF(QB[1], Bh, C[1][v4]); C[1][v4] = MF(QB[1], Bl, C[1][v4]); C[1][v4] = MF(QB[3], Bh, C[1][v4]);
      }
    }
    #pragma unroll
    for (int nt = 0; nt < 2; ++nt)
      #pragma unroll
      for (int v4 = 0; v4 < 4; ++v4) {
        int v = (wv * 4 + v4) * 16 + l15;
        float bo = b_out[v];
        #pragma unroll
        for (int r = 0; r < 4; ++r) {
          int b = nt * 16 + l4 * 4 + r;
          out[((size_t)b * 256 + tp) * 256 + v] = C[nt][v4][r] + bo;
        }
      }
  }
}

extern "C" void kernel_launch(void* const* d_in, const int* in_sizes, int n_in,
                              void* d_out, int out_size, void* d_ws, size_t ws_size,
                              hipStream_t stream) {
  const int*   targets = (const int*)d_in[1];
  const float* h0_in   = (const float*)d_in[2];
  const float* c0_in   = (const float*)d_in[3];
  const float* h1_in   = (const float*)d_in[4];
  const float* c1_in   = (const float*)d_in[5];
  const float* emb     = (const float*)d_in[6];
  const float* W_ih0   = (const float*)d_in[7];
  const float* W_hh0   = (const float*)d_in[8];
  const float* b0      = (const float*)d_in[9];
  const float* W_ih1   = (const float*)d_in[10];
  const float* W_hh1   = (const float*)d_in[11];
  const float* b1      = (const float*)d_in[12];
  const float* W_out   = (const float*)d_in[13];
  const float* b_out   = (const float*)d_in[14];
  float* out = (float*)d_out;

  char* ws = (char*)d_ws;
  char*  WA0    = ws;                         // Whh0 A-frags hi/lo, 16MB
  char*  WA1    = ws + 16777216;              // Wih1
  char*  WA2    = ws + 33554432;              // Whh1
  char*  WoutB  = ws + 50331648;              // W_out B-frags, 1MB
  char*  embB   = ws + 51380224;              // emb B-frags, 1MB
  float* E0     = (float*)(ws + 52428800);    // 4MB f32
  float* b1i    = (float*)(ws + 56623104);    // 16KB
  int*   f0     = (int*)(ws + 56639488);      // flag array, 4KB (128 x stride 32B)
  int*   f1     = (int*)(ws + 56643584);      // flag array, 4KB
  char*  h0ring = ws + 56647680;              // 16 slots x 128KB
  char*  h1frag = ws + 58744832;              // 257 slots x 128KB
  char*  WAi0   = h1frag + 16777216;          // Wih0 A-frags, aliased into h1frag slots 128+
                                              // (consumed for E0 at start; slot 128 written at step 127)

  prep_misc <<<18,   256, 0, stream>>>(b1, b1i, f0, f1);
  prep_wfrag<<<8192, 256, 0, stream>>>(W_hh0, W_ih1, W_hh1, W_ih0, WA0, WA1, WA2, WAi0);
  prep_bfrag<<<256,  256, 0, stream>>>(emb, W_out, embB, WoutB);
  prep_hinit<<<32,   256, 0, stream>>>(h0_in, h1_in, h0ring, h1frag);

  hipFuncSetAttribute(reinterpret_cast<const void*>(lstm_persist),
                      hipFuncAttributeMaxDynamicSharedMemorySize, 143360);
  lstm_persist<<<256, 256, 143360, stream>>>(
      targets, c0_in, c1_in, b0, b_out,
      WA0, WA1, WA2, WAi0, WoutB, embB,
      E0, b1i, h0ring, h1frag, f0, f1, out);
}

// Round 4
// 2125.535 us; speedup vs baseline: 7.2282x; 1.1049x over previous
//
#include <hip/hip_runtime.h>
#include <cstdint>

// CharRNN 2-layer LSTM, B=32,T=256,H=1024,V=256. Persistent kernel, round 4:
//   wgs 0..127  = layer-0 chain (8 units each), Whh0 hi+lo frags in LDS
//   wgs 128..255= layer-1 chain (8 units each), Wih1/Whh1 hi frags in LDS, lo streamed from L2
//   h handoff: write-once slots (257 per layer), producers store sc0sc1 (write-through to L3),
//   consumers use PLAIN CACHED loads (first touch is post-flag -> L2 dedups the 16x per-XCD fanout).
//   h0 slots 1..128 alias the dead WA0 staging region; hence WA0/WAi0 are read ONLY via sc0sc1
//   (non-caching) and flags gate step 0 on all-wgs-staged.
//   math: mfma_f32_16x16x32_bf16 split-bf16 (hi*hi + hi*lo + lo*hi) ~ f32 accuracy. Identical to r3.

typedef float  f32x4 __attribute__((ext_vector_type(4)));
typedef short  s16x8 __attribute__((ext_vector_type(8)));

#define DEV __device__ __forceinline__

DEV unsigned short f2bf(float x){
  unsigned u = __builtin_bit_cast(unsigned, x);
  unsigned r = (u + 0x7fffu + ((u >> 16) & 1u)) >> 16;   // round-nearest-even
  return (unsigned short)r;
}
DEV float bf2f(unsigned short b){ return __builtin_bit_cast(float, ((unsigned)b) << 16); }

DEV s16x8 ld16(const void* p){ return *(const s16x8*)p; }

DEV f32x4 MF(s16x8 a, s16x8 b, f32x4 c){
  return __builtin_amdgcn_mfma_f32_16x16x32_bf16(a, b, c, 0, 0, 0);
}

// coherent (bypass L1/L2) 16B load — for addresses that will be overwritten later (WA0/WAi0)
#define LDC(dst, ptr)  asm volatile("global_load_dwordx4 %0, %1, off sc0 sc1" : "=v"(dst) : "v"(ptr))
#define LDC4(dst, ptr) asm volatile("global_load_dwordx4 %0, %1, off sc0 sc1" : "=v"(dst) : "v"(ptr))
// plain cached 16B load (participates in our vmcnt accounting)
#define LDP(dst, ptr)  asm volatile("global_load_dwordx4 %0, %1, off"         : "=v"(dst) : "v"(ptr))
#define WAITVM(n) do { asm volatile("s_waitcnt vmcnt(" #n ")" ::: "memory"); \
                       __builtin_amdgcn_sched_barrier(0); } while (0)
#define TRIPLE(Cmn, Ahm, Alm, Bhn, Bln) do { \
    Cmn = MF(Ahm, Bhn, Cmn); Cmn = MF(Ahm, Bln, Cmn); Cmn = MF(Alm, Bhn, Cmn); } while (0)

DEV void st2c(void* p, unsigned short v){   // coherent 2B store (write-through to L3)
  asm volatile("global_store_short %0, %1, off sc0 sc1" :: "v"(p), "v"((unsigned)v) : "memory");
}
DEV void set_flag(int* p, int v){
  __hip_atomic_store(p, v, __ATOMIC_RELAXED, __HIP_MEMORY_SCOPE_AGENT);
}
// wave-0 collective poll: all 128 flags (stride 8 ints) >= target
DEV void poll2(const int* f, int lane, int target){
  const int* p0 = f + lane * 8;
  const int* p1 = f + (64 + lane) * 8;
  for (;;) {
    int a = __hip_atomic_load(p0, __ATOMIC_RELAXED, __HIP_MEMORY_SCOPE_AGENT);
    int b = __hip_atomic_load(p1, __ATOMIC_RELAXED, __HIP_MEMORY_SCOPE_AGENT);
    if (__all((a >= target) && (b >= target))) break;
    __builtin_amdgcn_s_sleep(1);
  }
}
// h0 slot address: 0 -> s0 buf; 1..128 -> aliased over WA0; 129..256 -> hi buf
DEV char* h0slot(char* wa0, char* s0, char* hi, int s){
  return (s == 0) ? s0 : ((s <= 128) ? wa0 + ((size_t)(s - 1) << 17)
                                     : hi  + ((size_t)(s - 129) << 17));
}

// ---------------- prep: W[k][g*H+u] -> A-frag hi/lo bf16 [jb256][part2][ks32][64*16B] ----
__global__ void prep_wfrag(const float* __restrict__ W0, const float* __restrict__ W1,
                           const float* __restrict__ W2, const float* __restrict__ W3,
                           char* D0, char* D1, char* D2, char* D3) {
  int gid = blockIdx.x * 256 + threadIdx.x;       // 4*256*32*64 = 2M
  int lane = gid & 63, ks = (gid >> 6) & 31, jb = (gid >> 11) & 255, mat = gid >> 19;
  const float* S = (mat == 0) ? W0 : (mat == 1) ? W1 : (mat == 2) ? W2 : W3;
  char* D = (mat == 0) ? D0 : (mat == 1) ? D1 : (mat == 2) ? D2 : D3;
  int jp = jb * 16 + (lane & 15), u = jp >> 2, g = jp & 3;
  int kb = ks * 32 + (lane >> 4) * 8;
  s16x8 vh, vl;
  #pragma unroll
  for (int i = 0; i < 8; ++i) {
    float x = S[(kb + i) * 4096 + g * 1024 + u];
    unsigned short h = f2bf(x);
    vh[i] = (short)h;
    vl[i] = (short)f2bf(x - bf2f(h));
  }
  *(s16x8*)(D + (((jb * 2 + 0) * 32 + ks) << 10) + lane * 16) = vh;
  *(s16x8*)(D + (((jb * 2 + 1) * 32 + ks) << 10) + lane * 16) = vl;
}

// ---------------- prep: emb [v][k] and W_out [k][v] -> B-frag hi/lo [vb16][part2][ks32] ----
__global__ void prep_bfrag(const float* __restrict__ emb, const float* __restrict__ Wout,
                           char* Demb, char* Dwout) {
  int gid = blockIdx.x * 256 + threadIdx.x;       // 2*16*32*64 = 64K
  int lane = gid & 63, ks = (gid >> 6) & 31, vb = (gid >> 11) & 15, which = gid >> 15;
  int v = vb * 16 + (lane & 15), kb = ks * 32 + (lane >> 4) * 8;
  s16x8 vh, vl;
  #pragma unroll
  for (int i = 0; i < 8; ++i) {
    float x = which ? Wout[(kb + i) * 256 + v] : emb[v * 1024 + kb + i];
    unsigned short h = f2bf(x);
    vh[i] = (short)h;
    vl[i] = (short)f2bf(x - bf2f(h));
  }
  char* D = which ? Dwout : Demb;
  *(s16x8*)(D + (((vb * 2 + 0) * 32 + ks) << 10) + lane * 16) = vh;
  *(s16x8*)(D + (((vb * 2 + 1) * 32 + ks) << 10) + lane * 16) = vl;
}

// ---------------- prep: h0_in/h1_in [b][k] f32 -> h-frag slot0 [part2][nt2][ks32] ----
__global__ void prep_hinit(const float* __restrict__ h0, const float* __restrict__ h1,
                           char* h0s0, char* h1f) {
  int gid = blockIdx.x * 256 + threadIdx.x;       // 2*2*32*64 = 8192
  int lane = gid & 63, ks = (gid >> 6) & 31, nt = (gid >> 11) & 1, which = gid >> 12;
  const float* S = which ? h1 : h0;
  char* D = which ? h1f : h0s0;                   // slot 0 of each
  int b = nt * 16 + (lane & 15), kb = ks * 32 + (lane >> 4) * 8;
  s16x8 vh, vl;
  #pragma unroll
  for (int i = 0; i < 8; ++i) {
    float x = S[b * 1024 + kb + i];
    unsigned short h = f2bf(x);
    vh[i] = (short)h;
    vl[i] = (short)f2bf(x - bf2f(h));
  }
  *(s16x8*)(D + (((0 * 2 + nt) * 32 + ks) << 10) + lane * 16) = vh;
  *(s16x8*)(D + (((1 * 2 + nt) * 32 + ks) << 10) + lane * 16) = vl;
}

// ---------------- prep: flags = -1 (staging gate), gate-interleave b1 ----
__global__ void prep_misc(const float* __restrict__ b1, float* b1i, int* f0a, int* f1a) {
  int i = blockIdx.x * 256 + threadIdx.x;         // 4608
  if (i < 4096) b1i[i] = b1[(i & 3) * 1024 + (i >> 2)];
  if (i < 1024) { f0a[i] = -1; f1a[i] = -1; }
}

// ---------------- the persistent LSTM kernel ----------------
__global__ __launch_bounds__(256, 1) void lstm_persist(
    const int* __restrict__ tgt,
    const float* __restrict__ c0_in, const float* __restrict__ c1_in,
    const float* __restrict__ b0, const float* __restrict__ b_out,
    char* __restrict__ WA0, const char* __restrict__ WA1, const char* __restrict__ WA2,
    const char* __restrict__ WAi0, const char* __restrict__ WoutB, const char* __restrict__ embB,
    float* __restrict__ E0, const float* __restrict__ b1i,
    char* __restrict__ h0s0, char* __restrict__ h0hi, char* __restrict__ h1frag,
    int* __restrict__ f0, int* __restrict__ f1,
    float* __restrict__ out)
{
  extern __shared__ char smem[];                  // 128KB A-frags + 16KB reduce scratch
  const int tid = threadIdx.x, lane = tid & 63, wv = tid >> 6;
  const int wg = blockIdx.x;
  const bool isL0 = (wg < 128);
  const int wgl = isL0 ? wg : (wg - 128);
  const int l15 = lane & 15, l4 = lane >> 4;

  // one-time cross-replay safety: invalidate stale L1/L2 lines
  __builtin_amdgcn_fence(__ATOMIC_ACQUIRE, "agent");

  // ---- stage A-frags into LDS: L0 = Whh0 hi+lo (via sc-loads: WA0 becomes h0 slots!) ----
  if (isL0) {
    uint4 tmp[8];
    for (int blk = 0; blk < 4; ++blk) {
      #pragma unroll
      for (int q = 0; q < 8; ++q) {
        int idx = tid + (blk * 8 + q) * 256;
        int l16 = idx & 63, ks = (idx >> 6) & 31, mi = (idx >> 11) & 1, part = idx >> 12;
        LDC4(tmp[q], WA0 + ((((wgl * 2 + mi) * 2 + part) * 32 + ks) << 10) + l16 * 16);
      }
      WAITVM(0);
      #pragma unroll
      for (int q = 0; q < 8; ++q) {
        int idx = tid + (blk * 8 + q) * 256;
        int l16 = idx & 63, ks = (idx >> 6) & 31, mi = (idx >> 11) & 1, part = idx >> 12;
        *(uint4*)(smem + (((part * 2 + mi) * 32 + ks) << 10) + l16 * 16) = tmp[q];
      }
    }
  } else {
    // L1: Wih1/Whh1 hi parts; these addresses are never overwritten -> plain loads fine
    for (int idx = tid; idx < 8192; idx += 256) {
      int l16 = idx & 63, ks = (idx >> 6) & 31, mi = (idx >> 11) & 1, mat = idx >> 12;
      const char* W = mat ? WA2 : WA1;
      uint4 v = *(const uint4*)(W + ((((wgl * 2 + mi) * 2 + 0) * 32 + ks) << 10) + l16 * 16);
      *(uint4*)(smem + (((mat * 2 + mi) * 32 + ks) << 10) + l16 * 16) = v;
    }
  }

  // ---- E0 = emb @ Wih0 + b0, own 32 gate-cols only (L0 wgs). WAi0 via sc-loads (aliased). ----
  if (isL0) {
    f32x4 C[2][4];
    #pragma unroll
    for (int a = 0; a < 2; ++a)
      #pragma unroll
      for (int b = 0; b < 4; ++b) C[a][b] = 0.0f;
    for (int ks = 0; ks < 32; ++ks) {
      s16x8 Ah0, Ah1, Al0, Al1;
      LDC(Ah0, WAi0 + ((((wgl * 2 + 0) * 2 + 0) * 32 + ks) << 10) + lane * 16);
      LDC(Ah1, WAi0 + ((((wgl * 2 + 1) * 2 + 0) * 32 + ks) << 10) + lane * 16);
      LDC(Al0, WAi0 + ((((wgl * 2 + 0) * 2 + 1) * 32 + ks) << 10) + lane * 16);
      LDC(Al1, WAi0 + ((((wgl * 2 + 1) * 2 + 1) * 32 + ks) << 10) + lane * 16);
      WAITVM(0);
      #pragma unroll
      for (int v4 = 0; v4 < 4; ++v4) {
        int vb = wv * 4 + v4;
        s16x8 Bh = ld16(embB + (((vb * 2 + 0) * 32 + ks) << 10) + lane * 16);
        s16x8 Bl = ld16(embB + (((vb * 2 + 1) * 32 + ks) << 10) + lane * 16);
        TRIPLE(C[0][v4], Ah0, Al0, Bh, Bl);
        TRIPLE(C[1][v4], Ah1, Al1, Bh, Bl);
      }
    }
    #pragma unroll
    for (int mi = 0; mi < 2; ++mi) {
      int jb4 = wgl * 32 + mi * 16 + l4 * 4;      // 4 consecutive gate-cols
      int u = jb4 >> 2;
      f32x4 bb;
      #pragma unroll
      for (int r = 0; r < 4; ++r) bb[r] = b0[r * 1024 + u];
      #pragma unroll
      for (int v4 = 0; v4 < 4; ++v4) {
        int v = (wv * 4 + v4) * 16 + l15;
        *(f32x4*)(E0 + v * 4096 + jb4) = C[mi][v4] + bb;
      }
    }
  }

  // ---- c state: wave w in {0,1} holds mi=w ----
  float cst[2];
  if (wv < 2) {
    const float* cs = isL0 ? c0_in : c1_in;
    #pragma unroll
    for (int nt = 0; nt < 2; ++nt)
      cst[nt] = cs[(nt * 16 + l15) * 1024 + wgl * 8 + wv * 4 + l4];
  }
  __syncthreads();                                 // staging + E0 complete for this wg
  if (tid == 0) set_flag((isL0 ? f0 : f1) + wgl * 8, 0);   // "staged" release

  // ---- sequential recurrence ----
  for (int t = 0; t < 256; ++t) {
    const int s = t + 1;
    f32x4 C[2][2];
    #pragma unroll
    for (int a = 0; a < 2; ++a)
      #pragma unroll
      for (int b = 0; b < 2; ++b) C[a][b] = 0.0f;

    if (isL0) {
      if (wv == 0) poll2(f0, lane, t);             // all L0 staged (t=0) / step t-1 done
      __syncthreads();
      const char* Bb = h0slot(WA0, h0s0, h0hi, t);
      const int ksb = wv * 8;
      s16x8 P[3][4];
      #pragma unroll
      for (int q = 0; q < 4; ++q) LDP(P[0][q], Bb + ((q * 32 + ksb) << 10) + lane * 16);
      #pragma unroll
      for (int q = 0; q < 4; ++q) LDP(P[1][q], Bb + ((q * 32 + ksb + 1) << 10) + lane * 16);
      #pragma unroll
      for (int i = 0; i < 8; ++i) {
        const int ks = ksb + i;
        if (i < 6) {
          #pragma unroll
          for (int q = 0; q < 4; ++q) LDP(P[(i + 2) % 3][q], Bb + ((q * 32 + ks + 2) << 10) + lane * 16);
        }
        s16x8 Ah0 = ld16(smem + ((0 * 32 + ks) << 10) + lane * 16);
        s16x8 Ah1 = ld16(smem + ((1 * 32 + ks) << 10) + lane * 16);
        s16x8 Al0 = ld16(smem + ((2 * 32 + ks) << 10) + lane * 16);
        s16x8 Al1 = ld16(smem + ((3 * 32 + ks) << 10) + lane * 16);
        if (i < 6) { WAITVM(8); } else if (i == 6) { WAITVM(4); } else { WAITVM(0); }
        TRIPLE(C[0][0], Ah0, Al0, P[i % 3][0], P[i % 3][2]);
        TRIPLE(C[0][1], Ah0, Al0, P[i % 3][1], P[i % 3][3]);
        TRIPLE(C[1][0], Ah1, Al1, P[i % 3][0], P[i % 3][2]);
        TRIPLE(C[1][1], Ah1, Al1, P[i % 3][1], P[i % 3][3]);
      }
    } else {
      // ---- half 1: own-layer h1_{t-1} (f1>=t); overlaps L0's step t ----
      if (wv == 0) poll2(f1, lane, t);
      __syncthreads();
      {
        const char* Bb = h1frag + (size_t)t * 131072;
        const int ksb = wv * 8;
        s16x8 P[3][4], AL[3][2];
        #pragma unroll
        for (int d = 0; d < 2; ++d) {
          #pragma unroll
          for (int q = 0; q < 4; ++q) LDP(P[d][q], Bb + ((q * 32 + ksb + d) << 10) + lane * 16);
          LDP(AL[d][0], WA2 + ((((wgl * 2 + 0) * 2 + 1) * 32 + ksb + d) << 10) + lane * 16);
          LDP(AL[d][1], WA2 + ((((wgl * 2 + 1) * 2 + 1) * 32 + ksb + d) << 10) + lane * 16);
        }
        #pragma unroll
        for (int i = 0; i < 8; ++i) {
          const int ks = ksb + i;
          if (i < 6) {
            #pragma unroll
            for (int q = 0; q < 4; ++q) LDP(P[(i + 2) % 3][q], Bb + ((q * 32 + ks + 2) << 10) + lane * 16);
            LDP(AL[(i + 2) % 3][0], WA2 + ((((wgl * 2 + 0) * 2 + 1) * 32 + ks + 2) << 10) + lane * 16);
            LDP(AL[(i + 2) % 3][1], WA2 + ((((wgl * 2 + 1) * 2 + 1) * 32 + ks + 2) << 10) + lane * 16);
          }
          s16x8 Ah0 = ld16(smem + (((2 + 0) * 32 + ks) << 10) + lane * 16);
          s16x8 Ah1 = ld16(smem + (((2 + 1) * 32 + ks) << 10) + lane * 16);
          if (i < 6) { WAITVM(12); } else if (i == 6) { WAITVM(6); } else { WAITVM(0); }
          TRIPLE(C[0][0], Ah0, AL[i % 3][0], P[i % 3][0], P[i % 3][2]);
          TRIPLE(C[0][1], Ah0, AL[i % 3][0], P[i % 3][1], P[i % 3][3]);
          TRIPLE(C[1][0], Ah1, AL[i % 3][1], P[i % 3][0], P[i % 3][2]);
          TRIPLE(C[1][1], Ah1, AL[i % 3][1], P[i % 3][1], P[i % 3][3]);
        }
      }
      // ---- half 0: h0_t from layer 0 (f0>=s) ----
      if (wv == 0) poll2(f0, lane, s);
      __syncthreads();
      {
        const char* Bb = h0slot(WA0, h0s0, h0hi, s);
        const int ksb = wv * 8;
        s16x8 P[3][4], AL[3][2];
        #pragma unroll
        for (int d = 0; d < 2; ++d) {
          #pragma unroll
          for (int q = 0; q < 4; ++q) LDP(P[d][q], Bb + ((q * 32 + ksb + d) << 10) + lane * 16);
          LDP(AL[d][0], WA1 + ((((wgl * 2 + 0) * 2 + 1) * 32 + ksb + d) << 10) + lane * 16);
          LDP(AL[d][1], WA1 + ((((wgl * 2 + 1) * 2 + 1) * 32 + ksb + d) << 10) + lane * 16);
        }
        #pragma unroll
        for (int i = 0; i < 8; ++i) {
          const int ks = ksb + i;
          if (i < 6) {
            #pragma unroll
            for (int q = 0; q < 4; ++q) LDP(P[(i + 2) % 3][q], Bb + ((q * 32 + ks + 2) << 10) + lane * 16);
            LDP(AL[(i + 2) % 3][0], WA1 + ((((wgl * 2 + 0) * 2 + 1) * 32 + ks + 2) << 10) + lane * 16);
            LDP(AL[(i + 2) % 3][1], WA1 + ((((wgl * 2 + 1) * 2 + 1) * 32 + ks + 2) << 10) + lane * 16);
          }
          s16x8 Ah0 = ld16(smem + (((0 + 0) * 32 + ks) << 10) + lane * 16);
          s16x8 Ah1 = ld16(smem + (((0 + 1) * 32 + ks) << 10) + lane * 16);
          if (i < 6) { WAITVM(12); } else if (i == 6) { WAITVM(6); } else { WAITVM(0); }
          TRIPLE(C[0][0], Ah0, AL[i % 3][0], P[i % 3][0], P[i % 3][2]);
          TRIPLE(C[0][1], Ah0, AL[i % 3][0], P[i % 3][1], P[i % 3][3]);
          TRIPLE(C[1][0], Ah1, AL[i % 3][1], P[i % 3][0], P[i % 3][2]);
          TRIPLE(C[1][1], Ah1, AL[i % 3][1], P[i % 3][1], P[i % 3][3]);
        }
      }
    }

    // ---- K-split reduction: all waves dump partials, waves 0/1 finish mi=wv ----
    #pragma unroll
    for (int mi = 0; mi < 2; ++mi)
      #pragma unroll
      for (int nt = 0; nt < 2; ++nt)
        *(f32x4*)(smem + 131072 + ((wv * 4 + mi * 2 + nt) << 10) + lane * 16) = C[mi][nt];
    __syncthreads();

    if (wv < 2) {
      const int mi = wv;
      char* hd = isL0 ? h0slot(WA0, h0s0, h0hi, s)
                      : (h1frag + (size_t)s * 131072);
      #pragma unroll
      for (int nt = 0; nt < 2; ++nt) {
        f32x4 z = {0.f, 0.f, 0.f, 0.f};
        #pragma unroll
        for (int p = 0; p < 4; ++p)
          z += *(const f32x4*)(smem + 131072 + ((p * 4 + mi * 2 + nt) << 10) + lane * 16);
        if (isL0) {
          int tv = tgt[(nt * 16 + l15) * 256 + t];
          z += *(const f32x4*)(E0 + tv * 4096 + wgl * 32 + mi * 16 + l4 * 4);
        } else {
          z += *(const f32x4*)(b1i + wgl * 32 + mi * 16 + l4 * 4);
        }
        float ig = 1.f / (1.f + __expf(-z[0]));
        float fg = 1.f / (1.f + __expf(-z[1]));
        float og = 1.f / (1.f + __expf(-z[3]));
        float cn = fg * cst[nt] + ig * tanhf(z[2]);
        float hn = og * tanhf(cn);
        cst[nt] = cn;
        unsigned short hb = f2bf(hn);
        unsigned short lb = f2bf(hn - bf2f(hb));
        int base = ((0 * 2 + nt) * 32 + (wgl >> 2)) * 1024 + ((wgl & 3) * 16 + l15) * 16 + (mi * 4 + l4) * 2;
        st2c(hd + base, hb);
        st2c(hd + base + 65536, lb);
        if (t == 255) {
          int u = wgl * 8 + mi * 4 + l4, b = nt * 16 + l15;
          int off = isL0 ? 0 : 65536;
          out[2097152 + off + b * 1024 + u] = hn;
          out[2097152 + off + 32768 + b * 1024 + u] = cn;
        }
      }
      asm volatile("s_waitcnt vmcnt(0)" ::: "memory");   // h stores at coherence point
    }
    __syncthreads();                                      // both writer waves drained
    if (tid == 0) set_flag((isL0 ? f0 : f1) + wgl * 8, s);
  }

  // ---- projection: logits[b][t][v] = h1_t @ W_out + b_out ; one t per CU ----
  {
    const int tp = isL0 ? (128 + wgl) : wgl;       // L1 wgs take early t's (already done)
    if (wv == 0) poll2(f1, lane, tp + 1);
    __syncthreads();
    const char* A = h1frag + (size_t)(tp + 1) * 131072;
    f32x4 C[2][4];
    #pragma unroll
    for (int a = 0; a < 2; ++a)
      #pragma unroll
      for (int b = 0; b < 4; ++b) C[a][b] = 0.0f;
    s16x8 QA[4], QB[4];
    #pragma unroll
    for (int q = 0; q < 4; ++q) LDP(QA[q], A + ((q * 32 + 0) << 10) + lane * 16);
    for (int kk = 0; kk < 16; ++kk) {
      const int ks = kk * 2;
      #pragma unroll
      for (int q = 0; q < 4; ++q) LDP(QB[q], A + ((q * 32 + ks + 1) << 10) + lane * 16);
      asm volatile("s_waitcnt vmcnt(4)" ::: "memory");
      __builtin_amdgcn_sched_barrier(0);
      #pragma unroll
      for (int v4 = 0; v4 < 4; ++v4) {
        int vb = wv * 4 + v4;
        s16x8 Bh = ld16(WoutB + (((vb * 2 + 0) * 32 + ks) << 10) + lane * 16);
        s16x8 Bl = ld16(WoutB + (((vb * 2 + 1) * 32 + ks) << 10) + lane * 16);
        C[0][v4] = MF(QA[0], Bh, C[0][v4]); C[0][v4] = MF(QA[0], Bl, C[0][v4]); C[0][v4] = MF(QA[2], Bh, C[0][v4]);
        C[1][v4] = MF(QA[1], Bh, C[1][v4]); C[1][v4] = MF(QA[1], Bl, C[1][v4]); C[1][v4] = MF(QA[3], Bh, C[1][v4]);
      }
      if (kk < 15) {
        #pragma unroll
        for (int q = 0; q < 4; ++q) LDP(QA[q], A + ((q * 32 + ks + 2) << 10) + lane * 16);
        asm volatile("s_waitcnt vmcnt(4)" ::: "memory");
      } else {
        asm volatile("s_waitcnt vmcnt(0)" ::: "memory");
      }
      __builtin_amdgcn_sched_barrier(0);
      #pragma unroll
      for (int v4 = 0; v4 < 4; ++v4) {
        int vb = wv * 4 + v4;
        s16x8 Bh = ld16(WoutB + (((vb * 2 + 0) * 32 + ks + 1) << 10) + lane * 16);
        s16x8 Bl = ld16(WoutB + (((vb * 2 + 1) * 32 + ks + 1) << 10) + lane * 16);
        C[0][v4] = MF(QB[0], Bh, C[0][v4]); C[0][v4] = MF(QB[0], Bl, C[0][v4]); C[0][v4] = MF(QB[2], Bh, C[0][v4]);
        C[1][v4] = MF(QB[1], Bh, C[1][v4]); C[1][v4] = MF(QB[1], Bl, C[1][v4]); C[1][v4] = MF(QB[3], Bh, C[1][v4]);
      }
    }
    #pragma unroll
    for (int nt = 0; nt < 2; ++nt)
      #pragma unroll
      for (int v4 = 0; v4 < 4; ++v4) {
        int v = (wv * 4 + v4) * 16 + l15;
        float bo = b_out[v];
        #pragma unroll
        for (int r = 0; r < 4; ++r) {
          int b = nt * 16 + l4 * 4 + r;
          out[((size_t)b * 256 + tp) * 256 + v] = C[nt][v4][r] + bo;
        }
      }
  }
}

extern "C" void kernel_launch(void* const* d_in, const int* in_sizes, int n_in,
                              void* d_out, int out_size, void* d_ws, size_t ws_size,
                              hipStream_t stream) {
  const int*   targets = (const int*)d_in[1];
  const float* h0_in   = (const float*)d_in[2];
  const float* c0_in   = (const float*)d_in[3];
  const float* h1_in   = (const float*)d_in[4];
  const float* c1_in   = (const float*)d_in[5];
  const float* emb     = (const float*)d_in[6];
  const float* W_ih0   = (const float*)d_in[7];
  const float* W_hh0   = (const float*)d_in[8];
  const float* b0      = (const float*)d_in[9];
  const float* W_ih1   = (const float*)d_in[10];
  const float* W_hh1   = (const float*)d_in[11];
  const float* b1      = (const float*)d_in[12];
  const float* W_out   = (const float*)d_in[13];
  const float* b_out   = (const float*)d_in[14];
  float* out = (float*)d_out;

  char* ws = (char*)d_ws;
  char*  WA0    = ws;                         // Whh0 A-frags hi/lo 16MB; becomes h0 slots 1..128
  char*  WA1    = ws + 16777216;              // Wih1 (hi staged, lo streamed)
  char*  WA2    = ws + 33554432;              // Whh1
  char*  WoutB  = ws + 50331648;              // W_out B-frags, 1MB
  char*  embB   = ws + 51380224;              // emb B-frags, 1MB
  float* E0     = (float*)(ws + 52428800);    // 4MB f32
  float* b1i    = (float*)(ws + 56623104);    // 16KB
  int*   f0     = (int*)(ws + 56639488);      // flag array, 4KB (128 x stride 32B)
  int*   f1     = (int*)(ws + 56643584);      // flag array, 4KB
  char*  h0s0   = ws + 56647680;              // h0 slot 0, 128KB
  char*  h0hi   = ws + 56778752;              // h0 slots 129..256, 16MB
  char*  h1frag = ws + 73555968;              // 257 slots x 128KB (~33.7MB) -> end ~102.3MB
  char*  WAi0   = h1frag + 16777216;          // Wih0 A-frags alias h1 slots 128..255
                                              // (read via sc-loads at E0; slot 128 written step 127)

  prep_misc <<<18,   256, 0, stream>>>(b1, b1i, f0, f1);
  prep_wfrag<<<8192, 256, 0, stream>>>(W_hh0, W_ih1, W_hh1, W_ih0, WA0, WA1, WA2, WAi0);
  prep_bfrag<<<256,  256, 0, stream>>>(emb, W_out, embB, WoutB);
  prep_hinit<<<32,   256, 0, stream>>>(h0_in, h1_in, h0s0, h1frag);

  hipFuncSetAttribute(reinterpret_cast<const void*>(lstm_persist),
                      hipFuncAttributeMaxDynamicSharedMemorySize, 147456);
  lstm_persist<<<256, 256, 147456, stream>>>(
      targets, c0_in, c1_in, b0, b_out,
      WA0, WA1, WA2, WAi0, WoutB, embB,
      E0, b1i, h0s0, h0hi, h1frag, f0, f1, out);
}

// Round 6
// 1872.840 us; speedup vs baseline: 8.2034x; 1.1349x over previous
//
#include <hip/hip_runtime.h>
#include <cstdint>

// CharRNN 2-layer LSTM, B=32,T=256,H=1024,V=256. Persistent kernel, round 5 (fixed):
//   wgs 0..127  = layer-0 chain (8 units each), Whh0 hi+lo frags in LDS
//   wgs 128..255= layer-1 chain (8 units each): waves 0,1 = h1@Whh1 (hi in LDS, lo streamed),
//                 waves 2,3 = h0@Wih1 — the two halves run in PARALLEL (was serial).
//   Per step: all 4 waves poll flags directly; compute; dump partials; syncA;
//   4-wave cell epilogue; repack h into 1KB LDS; syncB; wave0 stores 4x256B coalesced
//   sc0sc1 + vmcnt(0) + flag. h slots write-once (257/layer); h0 slots 1..128 alias WA0.
//   math: mfma_f32_16x16x32_bf16 split-bf16 (hi*hi + hi*lo + lo*hi) ~ f32 accuracy.

typedef float    f32x4 __attribute__((ext_vector_type(4)));
typedef short    s16x8 __attribute__((ext_vector_type(8)));
typedef unsigned u32x4 __attribute__((ext_vector_type(4)));

#define DEV __device__ __forceinline__

DEV unsigned short f2bf(float x){
  unsigned u = __builtin_bit_cast(unsigned, x);
  unsigned r = (u + 0x7fffu + ((u >> 16) & 1u)) >> 16;   // round-nearest-even
  return (unsigned short)r;
}
DEV float bf2f(unsigned short b){ return __builtin_bit_cast(float, ((unsigned)b) << 16); }

DEV s16x8 ld16(const void* p){ return *(const s16x8*)p; }

DEV f32x4 MF(s16x8 a, s16x8 b, f32x4 c){
  return __builtin_amdgcn_mfma_f32_16x16x32_bf16(a, b, c, 0, 0, 0);
}

// coherent (bypass L1/L2) 16B load — only for WA0/WAi0 (aliased regions)
#define LDC(dst, ptr)  asm volatile("global_load_dwordx4 %0, %1, off sc0 sc1" : "=v"(dst) : "v"(ptr))
// plain cached 16B load (participates in our vmcnt accounting)
#define LDP(dst, ptr)  asm volatile("global_load_dwordx4 %0, %1, off"         : "=v"(dst) : "v"(ptr))
#define WAITVM(n) do { asm volatile("s_waitcnt vmcnt(" #n ")" ::: "memory"); \
                       __builtin_amdgcn_sched_barrier(0); } while (0)
#define CFENCE()  asm volatile("" ::: "memory")
#define TRIPLE(Cmn, Ahm, Alm, Bhn, Bln) do { \
    Cmn = MF(Ahm, Bhn, Cmn); Cmn = MF(Ahm, Bln, Cmn); Cmn = MF(Alm, Bhn, Cmn); } while (0)

DEV void st16c(void* p, u32x4 v){   // coherent 16B store (write-through to L3)
  asm volatile("global_store_dwordx4 %0, %1, off sc0 sc1" :: "v"(p), "v"(v) : "memory");
}
DEV void set_flag(int* p, int v){
  __hip_atomic_store(p, v, __ATOMIC_RELAXED, __HIP_MEMORY_SCOPE_AGENT);
}
// per-wave collective poll: all 128 flags (stride 8 ints) >= target
DEV void poll2(const int* f, int lane, int target){
  const int* p0 = f + lane * 8;
  const int* p1 = f + (64 + lane) * 8;
  for (;;) {
    int a = __hip_atomic_load(p0, __ATOMIC_RELAXED, __HIP_MEMORY_SCOPE_AGENT);
    int b = __hip_atomic_load(p1, __ATOMIC_RELAXED, __HIP_MEMORY_SCOPE_AGENT);
    if (__all((a >= target) && (b >= target))) break;
    __builtin_amdgcn_s_sleep(1);
  }
  CFENCE();
}
// h0 slot address: 0 -> s0 buf; 1..128 -> aliased over WA0; 129..256 -> hi buf
DEV char* h0slot(char* wa0, char* s0, char* hi, int s){
  return (s == 0) ? s0 : ((s <= 128) ? wa0 + ((size_t)(s - 1) << 17)
                                     : hi  + ((size_t)(s - 129) << 17));
}

// ---------------- prep: W[k][g*H+u] -> A-frag hi/lo bf16 [jb256][part2][ks32][64*16B] ----
__global__ void prep_wfrag(const float* __restrict__ W0, const float* __restrict__ W1,
                           const float* __restrict__ W2, const float* __restrict__ W3,
                           char* D0, char* D1, char* D2, char* D3) {
  int gid = blockIdx.x * 256 + threadIdx.x;       // 4*256*32*64 = 2M
  int lane = gid & 63, ks = (gid >> 6) & 31, jb = (gid >> 11) & 255, mat = gid >> 19;
  const float* S = (mat == 0) ? W0 : (mat == 1) ? W1 : (mat == 2) ? W2 : W3;
  char* D = (mat == 0) ? D0 : (mat == 1) ? D1 : (mat == 2) ? D2 : D3;
  int jp = jb * 16 + (lane & 15), u = jp >> 2, g = jp & 3;
  int kb = ks * 32 + (lane >> 4) * 8;
  s16x8 vh, vl;
  #pragma unroll
  for (int i = 0; i < 8; ++i) {
    float x = S[(kb + i) * 4096 + g * 1024 + u];
    unsigned short h = f2bf(x);
    vh[i] = (short)h;
    vl[i] = (short)f2bf(x - bf2f(h));
  }
  *(s16x8*)(D + (((jb * 2 + 0) * 32 + ks) << 10) + lane * 16) = vh;
  *(s16x8*)(D + (((jb * 2 + 1) * 32 + ks) << 10) + lane * 16) = vl;
}

// ---------------- prep: emb [v][k] and W_out [k][v] -> B-frag hi/lo [vb16][part2][ks32] ----
__global__ void prep_bfrag(const float* __restrict__ emb, const float* __restrict__ Wout,
                           char* Demb, char* Dwout) {
  int gid = blockIdx.x * 256 + threadIdx.x;       // 2*16*32*64 = 64K
  int lane = gid & 63, ks = (gid >> 6) & 31, vb = (gid >> 11) & 15, which = gid >> 15;
  int v = vb * 16 + (lane & 15), kb = ks * 32 + (lane >> 4) * 8;
  s16x8 vh, vl;
  #pragma unroll
  for (int i = 0; i < 8; ++i) {
    float x = which ? Wout[(kb + i) * 256 + v] : emb[v * 1024 + kb + i];
    unsigned short h = f2bf(x);
    vh[i] = (short)h;
    vl[i] = (short)f2bf(x - bf2f(h));
  }
  char* D = which ? Dwout : Demb;
  *(s16x8*)(D + (((vb * 2 + 0) * 32 + ks) << 10) + lane * 16) = vh;
  *(s16x8*)(D + (((vb * 2 + 1) * 32 + ks) << 10) + lane * 16) = vl;
}

// ---------------- prep: h0_in/h1_in [b][k] f32 -> h-frag slot0 [part2][nt2][ks32] ----
__global__ void prep_hinit(const float* __restrict__ h0, const float* __restrict__ h1,
                           char* h0s0, char* h1f) {
  int gid = blockIdx.x * 256 + threadIdx.x;       // 2*2*32*64 = 8192
  int lane = gid & 63, ks = (gid >> 6) & 31, nt = (gid >> 11) & 1, which = gid >> 12;
  const float* S = which ? h1 : h0;
  char* D = which ? h1f : h0s0;                   // slot 0 of each
  int b = nt * 16 + (lane & 15), kb = ks * 32 + (lane >> 4) * 8;
  s16x8 vh, vl;
  #pragma unroll
  for (int i = 0; i < 8; ++i) {
    float x = S[b * 1024 + kb + i];
    unsigned short h = f2bf(x);
    vh[i] = (short)h;
    vl[i] = (short)f2bf(x - bf2f(h));
  }
  *(s16x8*)(D + (((0 * 2 + nt) * 32 + ks) << 10) + lane * 16) = vh;
  *(s16x8*)(D + (((1 * 2 + nt) * 32 + ks) << 10) + lane * 16) = vl;
}

// ---------------- prep: flags = -1 (staging gate), gate-interleave b1 ----
__global__ void prep_misc(const float* __restrict__ b1, float* b1i, int* f0a, int* f1a) {
  int i = blockIdx.x * 256 + threadIdx.x;         // 4608
  if (i < 4096) b1i[i] = b1[(i & 3) * 1024 + (i >> 2)];
  if (i < 1024) { f0a[i] = -1; f1a[i] = -1; }
}

// ---------------- the persistent LSTM kernel ----------------
__global__ __launch_bounds__(256, 1) void lstm_persist(
    const int* __restrict__ tgt,
    const float* __restrict__ c0_in, const float* __restrict__ c1_in,
    const float* __restrict__ b0, const float* __restrict__ b_out,
    char* __restrict__ WA0, const char* __restrict__ WA1, const char* __restrict__ WA2,
    const char* __restrict__ WAi0, const char* __restrict__ WoutB, const char* __restrict__ embB,
    float* __restrict__ E0, const float* __restrict__ b1i,
    char* __restrict__ h0s0, char* __restrict__ h0hi, char* __restrict__ h1frag,
    int* __restrict__ f0, int* __restrict__ f1,
    float* __restrict__ out)
{
  extern __shared__ char smem[];     // 128KB A-frags + 16KB partials + 1KB repack
  constexpr int PART = 131072;
  constexpr int RP   = 131072 + 16384;
  const int tid = threadIdx.x, lane = tid & 63, wv = tid >> 6;
  const int wg = blockIdx.x;
  const bool isL0 = (wg < 128);
  const int wgl = isL0 ? wg : (wg - 128);
  const int l15 = lane & 15, l4 = lane >> 4;
  const int mi_e = wv >> 1, nt_e = wv & 1;        // epilogue role (mi, nt)

  // one-time cross-replay safety: invalidate stale L1/L2 lines
  __builtin_amdgcn_fence(__ATOMIC_ACQUIRE, "agent");

  // ---- stage A-frags into LDS: L0 = Whh0 hi+lo (sc-loads: WA0 becomes h0 slots!) ----
  if (isL0) {
    u32x4 tmp[8];
    for (int blk = 0; blk < 4; ++blk) {
      #pragma unroll
      for (int q = 0; q < 8; ++q) {
        int idx = tid + (blk * 8 + q) * 256;
        int l16 = idx & 63, ks = (idx >> 6) & 31, mi = (idx >> 11) & 1, part = idx >> 12;
        LDC(tmp[q], WA0 + ((((wgl * 2 + mi) * 2 + part) * 32 + ks) << 10) + l16 * 16);
      }
      WAITVM(0);
      #pragma unroll
      for (int q = 0; q < 8; ++q) {
        int idx = tid + (blk * 8 + q) * 256;
        int l16 = idx & 63, ks = (idx >> 6) & 31, mi = (idx >> 11) & 1, part = idx >> 12;
        *(u32x4*)(smem + (((part * 2 + mi) * 32 + ks) << 10) + l16 * 16) = tmp[q];
      }
    }
  } else {
    for (int idx = tid; idx < 8192; idx += 256) {
      int l16 = idx & 63, ks = (idx >> 6) & 31, mi = (idx >> 11) & 1, mat = idx >> 12;
      const char* W = mat ? WA2 : WA1;
      u32x4 v = *(const u32x4*)(W + ((((wgl * 2 + mi) * 2 + 0) * 32 + ks) << 10) + l16 * 16);
      *(u32x4*)(smem + (((mat * 2 + mi) * 32 + ks) << 10) + l16 * 16) = v;
    }
  }

  // ---- E0 = emb @ Wih0 + b0, own 32 gate-cols only (L0 wgs). WAi0 via sc-loads. ----
  if (isL0) {
    f32x4 C[2][4];
    #pragma unroll
    for (int a = 0; a < 2; ++a)
      #pragma unroll
      for (int b = 0; b < 4; ++b) C[a][b] = 0.0f;
    for (int ks = 0; ks < 32; ++ks) {
      s16x8 Ah0, Ah1, Al0, Al1;
      LDC(Ah0, WAi0 + ((((wgl * 2 + 0) * 2 + 0) * 32 + ks) << 10) + lane * 16);
      LDC(Ah1, WAi0 + ((((wgl * 2 + 1) * 2 + 0) * 32 + ks) << 10) + lane * 16);
      LDC(Al0, WAi0 + ((((wgl * 2 + 0) * 2 + 1) * 32 + ks) << 10) + lane * 16);
      LDC(Al1, WAi0 + ((((wgl * 2 + 1) * 2 + 1) * 32 + ks) << 10) + lane * 16);
      WAITVM(0);
      #pragma unroll
      for (int v4 = 0; v4 < 4; ++v4) {
        int vb = wv * 4 + v4;
        s16x8 Bh = ld16(embB + (((vb * 2 + 0) * 32 + ks) << 10) + lane * 16);
        s16x8 Bl = ld16(embB + (((vb * 2 + 1) * 32 + ks) << 10) + lane * 16);
        TRIPLE(C[0][v4], Ah0, Al0, Bh, Bl);
        TRIPLE(C[1][v4], Ah1, Al1, Bh, Bl);
      }
    }
    #pragma unroll
    for (int mi = 0; mi < 2; ++mi) {
      int jb4 = wgl * 32 + mi * 16 + l4 * 4;
      int u = jb4 >> 2;
      f32x4 bb;
      #pragma unroll
      for (int r = 0; r < 4; ++r) bb[r] = b0[r * 1024 + u];
      #pragma unroll
      for (int v4 = 0; v4 < 4; ++v4) {
        int v = (wv * 4 + v4) * 16 + l15;
        *(f32x4*)(E0 + v * 4096 + jb4) = C[mi][v4] + bb;
      }
    }
  }

  // ---- c state + L1 bias: one quadrant per wave ----
  float cst;
  {
    const float* cs = isL0 ? c0_in : c1_in;
    cst = cs[(nt_e * 16 + l15) * 1024 + wgl * 8 + mi_e * 4 + l4];
  }
  f32x4 b1z = {0.f, 0.f, 0.f, 0.f};
  if (!isL0) b1z = *(const f32x4*)(b1i + wgl * 32 + mi_e * 16 + (l4 << 2));

  __syncthreads();                                 // staging + E0 complete for this wg
  if (tid == 0) set_flag((isL0 ? f0 : f1) + wgl * 8, 0);   // "staged" release

  // ---- sequential recurrence ----
  for (int t = 0; t < 256; ++t) {
    const int s = t + 1;
    f32x4 C[2][2];
    #pragma unroll
    for (int a = 0; a < 2; ++a)
      #pragma unroll
      for (int b = 0; b < 2; ++b) C[a][b] = 0.0f;

    f32x4 e0v = {0.f, 0.f, 0.f, 0.f};

    if (isL0) {
      // prefetch epilogue operands (E0 static during loop; issued before poll)
      int tv = tgt[(nt_e * 16 + l15) * 256 + t];
      e0v = *(const f32x4*)(E0 + (size_t)tv * 4096 + wgl * 32 + mi_e * 16 + (l4 << 2));
      poll2(f0, lane, t);                          // all 4 waves poll directly
      const char* Bb = h0slot(WA0, h0s0, h0hi, t);
      const int ksb = wv * 8;
      s16x8 P[3][4];
      #pragma unroll
      for (int d = 0; d < 2; ++d)
        #pragma unroll
        for (int q = 0; q < 4; ++q) LDP(P[d][q], Bb + ((q * 32 + ksb + d) << 10) + lane * 16);
      #pragma unroll
      for (int i = 0; i < 8; ++i) {
        const int ks = ksb + i;
        if (i < 6) {
          #pragma unroll
          for (int q = 0; q < 4; ++q) LDP(P[(i + 2) % 3][q], Bb + ((q * 32 + ks + 2) << 10) + lane * 16);
        }
        s16x8 Ah0 = ld16(smem + ((0 * 32 + ks) << 10) + lane * 16);
        s16x8 Ah1 = ld16(smem + ((1 * 32 + ks) << 10) + lane * 16);
        s16x8 Al0 = ld16(smem + ((2 * 32 + ks) << 10) + lane * 16);
        s16x8 Al1 = ld16(smem + ((3 * 32 + ks) << 10) + lane * 16);
        if (i < 6) { WAITVM(8); } else if (i == 6) { WAITVM(4); } else { WAITVM(0); }
        TRIPLE(C[0][0], Ah0, Al0, P[i % 3][0], P[i % 3][2]);
        TRIPLE(C[0][1], Ah0, Al0, P[i % 3][1], P[i % 3][3]);
        TRIPLE(C[1][0], Ah1, Al1, P[i % 3][0], P[i % 3][2]);
        TRIPLE(C[1][1], Ah1, Al1, P[i % 3][1], P[i % 3][3]);
      }
    } else {
      // L1: waves 0,1 = h1_{t-1}@Whh1 ; waves 2,3 = h0_t@Wih1 — in parallel
      const int mat = (wv < 2) ? 1 : 0;
      if (wv < 2) poll2(f1, lane, t); else poll2(f0, lane, s);
      const char* Bb  = (wv < 2) ? (h1frag + (size_t)t * 131072)
                                 : h0slot(WA0, h0s0, h0hi, s);
      const char* ALb = (wv < 2) ? WA2 : WA1;
      const int ksb = (wv & 1) * 16;
      s16x8 P[3][4], AL[3][2];
      #pragma unroll
      for (int d = 0; d < 2; ++d) {
        #pragma unroll
        for (int q = 0; q < 4; ++q) LDP(P[d][q], Bb + ((q * 32 + ksb + d) << 10) + lane * 16);
        LDP(AL[d][0], ALb + ((((wgl * 2 + 0) * 2 + 1) * 32 + ksb + d) << 10) + lane * 16);
        LDP(AL[d][1], ALb + ((((wgl * 2 + 1) * 2 + 1) * 32 + ksb + d) << 10) + lane * 16);
      }
      #pragma unroll
      for (int i = 0; i < 16; ++i) {
        const int ks = ksb + i;
        if (i < 14) {
          #pragma unroll
          for (int q = 0; q < 4; ++q) LDP(P[(i + 2) % 3][q], Bb + ((q * 32 + ks + 2) << 10) + lane * 16);
          LDP(AL[(i + 2) % 3][0], ALb + ((((wgl * 2 + 0) * 2 + 1) * 32 + ks + 2) << 10) + lane * 16);
          LDP(AL[(i + 2) % 3][1], ALb + ((((wgl * 2 + 1) * 2 + 1) * 32 + ks + 2) << 10) + lane * 16);
        }
        s16x8 Ah0 = ld16(smem + (((mat * 2 + 0) * 32 + ks) << 10) + lane * 16);
        s16x8 Ah1 = ld16(smem + (((mat * 2 + 1) * 32 + ks) << 10) + lane * 16);
        if (i < 14) { WAITVM(12); } else if (i == 14) { WAITVM(6); } else { WAITVM(0); }
        TRIPLE(C[0][0], Ah0, AL[i % 3][0], P[i % 3][0], P[i % 3][2]);
        TRIPLE(C[0][1], Ah0, AL[i % 3][0], P[i % 3][1], P[i % 3][3]);
        TRIPLE(C[1][0], Ah1, AL[i % 3][1], P[i % 3][0], P[i % 3][2]);
        TRIPLE(C[1][1], Ah1, AL[i % 3][1], P[i % 3][1], P[i % 3][3]);
      }
    }

    // ---- dump partials ----
    #pragma unroll
    for (int mi = 0; mi < 2; ++mi)
      #pragma unroll
      for (int nt = 0; nt < 2; ++nt)
        *(f32x4*)(smem + PART + ((wv * 4 + mi * 2 + nt) << 10) + lane * 16) = C[mi][nt];
    __syncthreads();                               // syncA

    // ---- 4-wave epilogue: wave (mi_e, nt_e) ----
    {
      f32x4 z = *(const f32x4*)(smem + PART + ((0 * 4 + wv) << 10) + lane * 16);
      #pragma unroll
      for (int w = 1; w < 4; ++w)
        z += *(const f32x4*)(smem + PART + ((w * 4 + wv) << 10) + lane * 16);
      z += isL0 ? e0v : b1z;
      float ig = 1.f / (1.f + __expf(-z[0]));
      float fg = 1.f / (1.f + __expf(-z[1]));
      float og = 1.f / (1.f + __expf(-z[3]));
      float cn = fg * cst + ig * tanhf(z[2]);
      float hn = og * tanhf(cn);
      cst = cn;
      unsigned short hb = f2bf(hn);
      unsigned short lb = f2bf(hn - bf2f(hb));
      // repack [part2][nt2][l15][8 shorts]
      *(short*)(smem + RP + ((0 + nt_e) * 16 + l15) * 16 + (mi_e * 4 + l4) * 2) = (short)hb;
      *(short*)(smem + RP + ((2 + nt_e) * 16 + l15) * 16 + (mi_e * 4 + l4) * 2) = (short)lb;
      if (t == 255) {
        int u = wgl * 8 + mi_e * 4 + l4, b = nt_e * 16 + l15;
        int off = isL0 ? 0 : 65536;
        out[2097152 + off + b * 1024 + u] = hn;
        out[2097152 + off + 32768 + b * 1024 + u] = cn;
      }
    }
    __syncthreads();                               // syncB

    // ---- wave0: coalesced 1KB h-frag store + drain + flag ----
    if (wv == 0) {
      char* hd = isL0 ? h0slot(WA0, h0s0, h0hi, s)
                      : (h1frag + (size_t)s * 131072);
      u32x4 v = *(const u32x4*)(smem + RP + lane * 16);
      char* dst = hd + (((lane >> 4) * 32 + (wgl >> 2)) << 10) + ((wgl & 3) * 16 + l15) * 16;
      st16c(dst, v);
      asm volatile("s_waitcnt vmcnt(0)" ::: "memory");
      if (lane == 0) set_flag((isL0 ? f0 : f1) + wgl * 8, s);
    }
  }

  // ---- projection: logits[b][t][v] = h1_t @ W_out + b_out ; one t per CU ----
  {
    const int tp = isL0 ? (128 + wgl) : wgl;       // L1 wgs take early t's (already done)
    poll2(f1, lane, tp + 1);
    const char* A = h1frag + (size_t)(tp + 1) * 131072;
    f32x4 C[2][4];
    #pragma unroll
    for (int a = 0; a < 2; ++a)
      #pragma unroll
      for (int b = 0; b < 4; ++b) C[a][b] = 0.0f;
    s16x8 QA[4], QB[4];
    #pragma unroll
    for (int q = 0; q < 4; ++q) LDP(QA[q], A + ((q * 32 + 0) << 10) + lane * 16);
    for (int kk = 0; kk < 16; ++kk) {
      const int ks = kk * 2;
      #pragma unroll
      for (int q = 0; q < 4; ++q) LDP(QB[q], A + ((q * 32 + ks + 1) << 10) + lane * 16);
      asm volatile("s_waitcnt vmcnt(4)" ::: "memory");
      __builtin_amdgcn_sched_barrier(0);
      #pragma unroll
      for (int v4 = 0; v4 < 4; ++v4) {
        int vb = wv * 4 + v4;
        s16x8 Bh = ld16(WoutB + (((vb * 2 + 0) * 32 + ks) << 10) + lane * 16);
        s16x8 Bl = ld16(WoutB + (((vb * 2 + 1) * 32 + ks) << 10) + lane * 16);
        C[0][v4] = MF(QA[0], Bh, C[0][v4]); C[0][v4] = MF(QA[0], Bl, C[0][v4]); C[0][v4] = MF(QA[2], Bh, C[0][v4]);
        C[1][v4] = MF(QA[1], Bh, C[1][v4]); C[1][v4] = MF(QA[1], Bl, C[1][v4]); C[1][v4] = MF(QA[3], Bh, C[1][v4]);
      }
      if (kk < 15) {
        #pragma unroll
        for (int q = 0; q < 4; ++q) LDP(QA[q], A + ((q * 32 + ks + 2) << 10) + lane * 16);
        asm volatile("s_waitcnt vmcnt(4)" ::: "memory");
      } else {
        asm volatile("s_waitcnt vmcnt(0)" ::: "memory");
      }
      __builtin_amdgcn_sched_barrier(0);
      #pragma unroll
      for (int v4 = 0; v4 < 4; ++v4) {
        int vb = wv * 4 + v4;
        s16x8 Bh = ld16(WoutB + (((vb * 2 + 0) * 32 + ks + 1) << 10) + lane * 16);
        s16x8 Bl = ld16(WoutB + (((vb * 2 + 1) * 32 + ks + 1) << 10) + lane * 16);
        C[0][v4] = MF(QB[0], Bh, C[0][v4]); C[0][v4] = MF(QB[0], Bl, C[0][v4]); C[0][v4] = MF(QB[2], Bh, C[0][v4]);
        C[1][v4] = MF(QB[1], Bh, C[1][v4]); C[1][v4] = MF(QB[1], Bl, C[1][v4]); C[1][v4] = MF(QB[3], Bh, C[1][v4]);
      }
    }
    #pragma unroll
    for (int nt = 0; nt < 2; ++nt)
      #pragma unroll
      for (int v4 = 0; v4 < 4; ++v4) {
        int v = (wv * 4 + v4) * 16 + l15;
        float bo = b_out[v];
        #pragma unroll
        for (int r = 0; r < 4; ++r) {
          int b = nt * 16 + l4 * 4 + r;
          out[((size_t)b * 256 + tp) * 256 + v] = C[nt][v4][r] + bo;
        }
      }
  }
}

extern "C" void kernel_launch(void* const* d_in, const int* in_sizes, int n_in,
                              void* d_out, int out_size, void* d_ws, size_t ws_size,
                              hipStream_t stream) {
  const int*   targets = (const int*)d_in[1];
  const float* h0_in   = (const float*)d_in[2];
  const float* c0_in   = (const float*)d_in[3];
  const float* h1_in   = (const float*)d_in[4];
  const float* c1_in   = (const float*)d_in[5];
  const float* emb     = (const float*)d_in[6];
  const float* W_ih0   = (const float*)d_in[7];
  const float* W_hh0   = (const float*)d_in[8];
  const float* b0      = (const float*)d_in[9];
  const float* W_ih1   = (const float*)d_in[10];
  const float* W_hh1   = (const float*)d_in[11];
  const float* b1      = (const float*)d_in[12];
  const float* W_out   = (const float*)d_in[13];
  const float* b_out   = (const float*)d_in[14];
  float* out = (float*)d_out;

  char* ws = (char*)d_ws;
  char*  WA0    = ws;                         // Whh0 A-frags hi/lo 16MB; becomes h0 slots 1..128
  char*  WA1    = ws + 16777216;              // Wih1 (hi staged, lo streamed)
  char*  WA2    = ws + 33554432;              // Whh1
  char*  WoutB  = ws + 50331648;              // W_out B-frags, 1MB
  char*  embB   = ws + 51380224;              // emb B-frags, 1MB
  float* E0     = (float*)(ws + 52428800);    // 4MB f32
  float* b1i    = (float*)(ws + 56623104);    // 16KB
  int*   f0     = (int*)(ws + 56639488);      // flag array, 4KB (128 x stride 32B)
  int*   f1     = (int*)(ws + 56643584);      // flag array, 4KB
  char*  h0s0   = ws + 56647680;              // h0 slot 0, 128KB
  char*  h0hi   = ws + 56778752;              // h0 slots 129..256, 16MB
  char*  h1frag = ws + 73555968;              // 257 slots x 128KB (~33.7MB) -> end ~102.3MB
  char*  WAi0   = h1frag + 16777216;          // Wih0 A-frags alias h1 slots 128..255
                                              // (read via sc-loads at E0; slot 128 written step 127)

  prep_misc <<<18,   256, 0, stream>>>(b1, b1i, f0, f1);
  prep_wfrag<<<8192, 256, 0, stream>>>(W_hh0, W_ih1, W_hh1, W_ih0, WA0, WA1, WA2, WAi0);
  prep_bfrag<<<256,  256, 0, stream>>>(emb, W_out, embB, WoutB);
  prep_hinit<<<32,   256, 0, stream>>>(h0_in, h1_in, h0s0, h1frag);

  hipFuncSetAttribute(reinterpret_cast<const void*>(lstm_persist),
                      hipFuncAttributeMaxDynamicSharedMemorySize, 148480);
  lstm_persist<<<256, 256, 148480, stream>>>(
      targets, c0_in, c1_in, b0, b_out,
      WA0, WA1, WA2, WAi0, WoutB, embB,
      E0, b1i, h0s0, h0hi, h1frag, f0, f1, out);
}

// Round 7
// 1722.947 us; speedup vs baseline: 8.9171x; 1.0870x over previous
//
#include <hip/hip_runtime.h>
#include <cstdint>

// CharRNN 2-layer LSTM, B=32,T=256,H=1024,V=256. Persistent kernel, round 7:
//   wgs 0..127  = layer-0 chain (8 units each), Whh0 hi+lo frags in LDS
//   wgs 128..255= layer-1 chain (8 units each): CRITICAL loop = h1@Whh1 on ALL 4 waves
//                 (8 iters each); h0@Wih1 prefetched ONE STEP AHEAD off-critical into zpre.
//   Projection assignment swapped: L0 wgs (finish first) take EARLY t (instant flags),
//   L1 wgs take late t; projection polls use slow sleep (kills tail spin storm).
//   h slots write-once (257/layer); h0 slots 1..128 alias WA0; flags via relaxed agent atomics.
//   math: mfma_f32_16x16x32_bf16 split-bf16 (hi*hi + hi*lo + lo*hi) ~ f32 accuracy.

typedef float    f32x4 __attribute__((ext_vector_type(4)));
typedef short    s16x8 __attribute__((ext_vector_type(8)));
typedef unsigned u32x4 __attribute__((ext_vector_type(4)));

#define DEV __device__ __forceinline__

DEV unsigned short f2bf(float x){
  unsigned u = __builtin_bit_cast(unsigned, x);
  unsigned r = (u + 0x7fffu + ((u >> 16) & 1u)) >> 16;   // round-nearest-even
  return (unsigned short)r;
}
DEV float bf2f(unsigned short b){ return __builtin_bit_cast(float, ((unsigned)b) << 16); }

DEV s16x8 ld16(const void* p){ return *(const s16x8*)p; }

DEV f32x4 MF(s16x8 a, s16x8 b, f32x4 c){
  return __builtin_amdgcn_mfma_f32_16x16x32_bf16(a, b, c, 0, 0, 0);
}

// coherent (bypass L1/L2) 16B load — only for WA0/WAi0 (aliased regions)
#define LDC(dst, ptr)  asm volatile("global_load_dwordx4 %0, %1, off sc0 sc1" : "=v"(dst) : "v"(ptr))
// plain cached 16B load (participates in our vmcnt accounting)
#define LDP(dst, ptr)  asm volatile("global_load_dwordx4 %0, %1, off"         : "=v"(dst) : "v"(ptr))
#define WAITVM(n) do { asm volatile("s_waitcnt vmcnt(" #n ")" ::: "memory"); \
                       __builtin_amdgcn_sched_barrier(0); } while (0)
#define CFENCE()  asm volatile("" ::: "memory")
#define TRIPLE(Cmn, Ahm, Alm, Bhn, Bln) do { \
    Cmn = MF(Ahm, Bhn, Cmn); Cmn = MF(Ahm, Bln, Cmn); Cmn = MF(Alm, Bhn, Cmn); } while (0)

DEV void st16c(void* p, u32x4 v){   // coherent 16B store (write-through)
  asm volatile("global_store_dwordx4 %0, %1, off sc0 sc1" :: "v"(p), "v"(v) : "memory");
}
DEV void set_flag(int* p, int v){
  __hip_atomic_store(p, v, __ATOMIC_RELAXED, __HIP_MEMORY_SCOPE_AGENT);
}
// collective poll: all 128 flags (stride 8 ints) >= target. SLP = sleep amount.
template<int SLP>
DEV void pollT(const int* f, int lane, int target){
  const int* p0 = f + lane * 8;
  const int* p1 = f + (64 + lane) * 8;
  for (;;) {
    int a = __hip_atomic_load(p0, __ATOMIC_RELAXED, __HIP_MEMORY_SCOPE_AGENT);
    int b = __hip_atomic_load(p1, __ATOMIC_RELAXED, __HIP_MEMORY_SCOPE_AGENT);
    if (__all((a >= target) && (b >= target))) break;
    __builtin_amdgcn_s_sleep(SLP);
  }
  CFENCE();
}
// h0 slot address: 0 -> s0 buf; 1..128 -> aliased over WA0; 129..256 -> hi buf
DEV char* h0slot(char* wa0, char* s0, char* hi, int s){
  return (s == 0) ? s0 : ((s <= 128) ? wa0 + ((size_t)(s - 1) << 17)
                                     : hi  + ((size_t)(s - 129) << 17));
}

// 8-iteration half-GEMM: A hi from LDS (smemMat), A lo streamed from ALb, B 4 quarters from Bb
DEV void halfgemm8(const char* smemMat, const char* ALb, const char* Bb,
                   int wgl, int ksb, int lane, f32x4 (&C)[2][2]) {
  s16x8 P[3][4], AL[3][2];
  #pragma unroll
  for (int d = 0; d < 2; ++d) {
    #pragma unroll
    for (int q = 0; q < 4; ++q) LDP(P[d][q], Bb + ((q * 32 + ksb + d) << 10) + lane * 16);
    LDP(AL[d][0], ALb + ((((wgl * 2 + 0) * 2 + 1) * 32 + ksb + d) << 10) + lane * 16);
    LDP(AL[d][1], ALb + ((((wgl * 2 + 1) * 2 + 1) * 32 + ksb + d) << 10) + lane * 16);
  }
  #pragma unroll
  for (int i = 0; i < 8; ++i) {
    const int ks = ksb + i;
    if (i < 6) {
      #pragma unroll
      for (int q = 0; q < 4; ++q) LDP(P[(i + 2) % 3][q], Bb + ((q * 32 + ks + 2) << 10) + lane * 16);
      LDP(AL[(i + 2) % 3][0], ALb + ((((wgl * 2 + 0) * 2 + 1) * 32 + ks + 2) << 10) + lane * 16);
      LDP(AL[(i + 2) % 3][1], ALb + ((((wgl * 2 + 1) * 2 + 1) * 32 + ks + 2) << 10) + lane * 16);
    }
    s16x8 Ah0 = ld16(smemMat + ((0 * 32 + ks) << 10) + lane * 16);
    s16x8 Ah1 = ld16(smemMat + ((1 * 32 + ks) << 10) + lane * 16);
    if (i < 6) { WAITVM(12); } else if (i == 6) { WAITVM(6); } else { WAITVM(0); }
    TRIPLE(C[0][0], Ah0, AL[i % 3][0], P[i % 3][0], P[i % 3][2]);
    TRIPLE(C[0][1], Ah0, AL[i % 3][0], P[i % 3][1], P[i % 3][3]);
    TRIPLE(C[1][0], Ah1, AL[i % 3][1], P[i % 3][0], P[i % 3][2]);
    TRIPLE(C[1][1], Ah1, AL[i % 3][1], P[i % 3][1], P[i % 3][3]);
  }
}

// ---------------- prep: W[k][g*H+u] -> A-frag hi/lo bf16 [jb256][part2][ks32][64*16B] ----
__global__ void prep_wfrag(const float* __restrict__ W0, const float* __restrict__ W1,
                           const float* __restrict__ W2, const float* __restrict__ W3,
                           char* D0, char* D1, char* D2, char* D3) {
  int gid = blockIdx.x * 256 + threadIdx.x;       // 4*256*32*64 = 2M
  int lane = gid & 63, ks = (gid >> 6) & 31, jb = (gid >> 11) & 255, mat = gid >> 19;
  const float* S = (mat == 0) ? W0 : (mat == 1) ? W1 : (mat == 2) ? W2 : W3;
  char* D = (mat == 0) ? D0 : (mat == 1) ? D1 : (mat == 2) ? D2 : D3;
  int jp = jb * 16 + (lane & 15), u = jp >> 2, g = jp & 3;
  int kb = ks * 32 + (lane >> 4) * 8;
  s16x8 vh, vl;
  #pragma unroll
  for (int i = 0; i < 8; ++i) {
    float x = S[(kb + i) * 4096 + g * 1024 + u];
    unsigned short h = f2bf(x);
    vh[i] = (short)h;
    vl[i] = (short)f2bf(x - bf2f(h));
  }
  *(s16x8*)(D + (((jb * 2 + 0) * 32 + ks) << 10) + lane * 16) = vh;
  *(s16x8*)(D + (((jb * 2 + 1) * 32 + ks) << 10) + lane * 16) = vl;
}

// ---------------- prep: emb [v][k] and W_out [k][v] -> B-frag hi/lo [vb16][part2][ks32] ----
__global__ void prep_bfrag(const float* __restrict__ emb, const float* __restrict__ Wout,
                           char* Demb, char* Dwout) {
  int gid = blockIdx.x * 256 + threadIdx.x;       // 2*16*32*64 = 64K
  int lane = gid & 63, ks = (gid >> 6) & 31, vb = (gid >> 11) & 15, which = gid >> 15;
  int v = vb * 16 + (lane & 15), kb = ks * 32 + (lane >> 4) * 8;
  s16x8 vh, vl;
  #pragma unroll
  for (int i = 0; i < 8; ++i) {
    float x = which ? Wout[(kb + i) * 256 + v] : emb[v * 1024 + kb + i];
    unsigned short h = f2bf(x);
    vh[i] = (short)h;
    vl[i] = (short)f2bf(x - bf2f(h));
  }
  char* D = which ? Dwout : Demb;
  *(s16x8*)(D + (((vb * 2 + 0) * 32 + ks) << 10) + lane * 16) = vh;
  *(s16x8*)(D + (((vb * 2 + 1) * 32 + ks) << 10) + lane * 16) = vl;
}

// ---------------- prep: h0_in/h1_in [b][k] f32 -> h-frag slot0 [part2][nt2][ks32] ----
__global__ void prep_hinit(const float* __restrict__ h0, const float* __restrict__ h1,
                           char* h0s0, char* h1f) {
  int gid = blockIdx.x * 256 + threadIdx.x;       // 2*2*32*64 = 8192
  int lane = gid & 63, ks = (gid >> 6) & 31, nt = (gid >> 11) & 1, which = gid >> 12;
  const float* S = which ? h1 : h0;
  char* D = which ? h1f : h0s0;                   // slot 0 of each
  int b = nt * 16 + (lane & 15), kb = ks * 32 + (lane >> 4) * 8;
  s16x8 vh, vl;
  #pragma unroll
  for (int i = 0; i < 8; ++i) {
    float x = S[b * 1024 + kb + i];
    unsigned short h = f2bf(x);
    vh[i] = (short)h;
    vl[i] = (short)f2bf(x - bf2f(h));
  }
  *(s16x8*)(D + (((0 * 2 + nt) * 32 + ks) << 10) + lane * 16) = vh;
  *(s16x8*)(D + (((1 * 2 + nt) * 32 + ks) << 10) + lane * 16) = vl;
}

// ---------------- prep: flags = -1 (staging gate), gate-interleave b1 ----
__global__ void prep_misc(const float* __restrict__ b1, float* b1i, int* f0a, int* f1a) {
  int i = blockIdx.x * 256 + threadIdx.x;         // 4608
  if (i < 4096) b1i[i] = b1[(i & 3) * 1024 + (i >> 2)];
  if (i < 1024) { f0a[i] = -1; f1a[i] = -1; }
}

// ---------------- the persistent LSTM kernel ----------------
__global__ __launch_bounds__(256, 1) void lstm_persist(
    const int* __restrict__ tgt,
    const float* __restrict__ c0_in, const float* __restrict__ c1_in,
    const float* __restrict__ b0, const float* __restrict__ b_out,
    char* __restrict__ WA0, const char* __restrict__ WA1, const char* __restrict__ WA2,
    const char* __restrict__ WAi0, const char* __restrict__ WoutB, const char* __restrict__ embB,
    float* __restrict__ E0, const float* __restrict__ b1i,
    char* __restrict__ h0s0, char* __restrict__ h0hi, char* __restrict__ h1frag,
    int* __restrict__ f0, int* __restrict__ f1,
    float* __restrict__ out)
{
  extern __shared__ char smem[];     // 128KB A-frags + 16KB partials + 1KB repack
  constexpr int PART = 131072;
  constexpr int RP   = 131072 + 16384;
  const int tid = threadIdx.x, lane = tid & 63, wv = tid >> 6;
  const int wg = blockIdx.x;
  const bool isL0 = (wg < 128);
  const int wgl = isL0 ? wg : (wg - 128);
  const int l15 = lane & 15, l4 = lane >> 4;
  const int mi_e = wv >> 1, nt_e = wv & 1;        // epilogue role (mi, nt)

  // one-time cross-replay safety: invalidate stale L1/L2 lines
  __builtin_amdgcn_fence(__ATOMIC_ACQUIRE, "agent");

  // ---- stage A-frags into LDS: L0 = Whh0 hi+lo (sc-loads: WA0 becomes h0 slots!) ----
  if (isL0) {
    u32x4 tmp[8];
    for (int blk = 0; blk < 4; ++blk) {
      #pragma unroll
      for (int q = 0; q < 8; ++q) {
        int idx = tid + (blk * 8 + q) * 256;
        int l16 = idx & 63, ks = (idx >> 6) & 31, mi = (idx >> 11) & 1, part = idx >> 12;
        LDC(tmp[q], WA0 + ((((wgl * 2 + mi) * 2 + part) * 32 + ks) << 10) + l16 * 16);
      }
      WAITVM(0);
      #pragma unroll
      for (int q = 0; q < 8; ++q) {
        int idx = tid + (blk * 8 + q) * 256;
        int l16 = idx & 63, ks = (idx >> 6) & 31, mi = (idx >> 11) & 1, part = idx >> 12;
        *(u32x4*)(smem + (((part * 2 + mi) * 32 + ks) << 10) + l16 * 16) = tmp[q];
      }
    }
  } else {
    for (int idx = tid; idx < 8192; idx += 256) {
      int l16 = idx & 63, ks = (idx >> 6) & 31, mi = (idx >> 11) & 1, mat = idx >> 12;
      const char* W = mat ? WA2 : WA1;
      u32x4 v = *(const u32x4*)(W + ((((wgl * 2 + mi) * 2 + 0) * 32 + ks) << 10) + l16 * 16);
      *(u32x4*)(smem + (((mat * 2 + mi) * 32 + ks) << 10) + l16 * 16) = v;
    }
  }

  // ---- E0 = emb @ Wih0 + b0, own 32 gate-cols only (L0 wgs). WAi0 via sc-loads. ----
  if (isL0) {
    f32x4 C[2][4];
    #pragma unroll
    for (int a = 0; a < 2; ++a)
      #pragma unroll
      for (int b = 0; b < 4; ++b) C[a][b] = 0.0f;
    for (int ks = 0; ks < 32; ++ks) {
      s16x8 Ah0, Ah1, Al0, Al1;
      LDC(Ah0, WAi0 + ((((wgl * 2 + 0) * 2 + 0) * 32 + ks) << 10) + lane * 16);
      LDC(Ah1, WAi0 + ((((wgl * 2 + 1) * 2 + 0) * 32 + ks) << 10) + lane * 16);
      LDC(Al0, WAi0 + ((((wgl * 2 + 0) * 2 + 1) * 32 + ks) << 10) + lane * 16);
      LDC(Al1, WAi0 + ((((wgl * 2 + 1) * 2 + 1) * 32 + ks) << 10) + lane * 16);
      WAITVM(0);
      #pragma unroll
      for (int v4 = 0; v4 < 4; ++v4) {
        int vb = wv * 4 + v4;
        s16x8 Bh = ld16(embB + (((vb * 2 + 0) * 32 + ks) << 10) + lane * 16);
        s16x8 Bl = ld16(embB + (((vb * 2 + 1) * 32 + ks) << 10) + lane * 16);
        TRIPLE(C[0][v4], Ah0, Al0, Bh, Bl);
        TRIPLE(C[1][v4], Ah1, Al1, Bh, Bl);
      }
    }
    #pragma unroll
    for (int mi = 0; mi < 2; ++mi) {
      int jb4 = wgl * 32 + mi * 16 + l4 * 4;
      int u = jb4 >> 2;
      f32x4 bb;
      #pragma unroll
      for (int r = 0; r < 4; ++r) bb[r] = b0[r * 1024 + u];
      #pragma unroll
      for (int v4 = 0; v4 < 4; ++v4) {
        int v = (wv * 4 + v4) * 16 + l15;
        *(f32x4*)(E0 + v * 4096 + jb4) = C[mi][v4] + bb;
      }
    }
  }

  // ---- c state + L1 bias: one quadrant per wave ----
  float cst;
  {
    const float* cs = isL0 ? c0_in : c1_in;
    cst = cs[(nt_e * 16 + l15) * 1024 + wgl * 8 + mi_e * 4 + l4];
  }
  f32x4 b1z = {0.f, 0.f, 0.f, 0.f};
  if (!isL0) b1z = *(const f32x4*)(b1i + wgl * 32 + mi_e * 16 + (l4 << 2));

  __syncthreads();                                 // staging + E0 complete for this wg
  if (tid == 0) set_flag((isL0 ? f0 : f1) + wgl * 8, 0);   // "staged" release

  // ---- sequential recurrence ----
  if (isL0) {
    for (int t = 0; t < 256; ++t) {
      const int s = t + 1;
      f32x4 C[2][2];
      #pragma unroll
      for (int a = 0; a < 2; ++a)
        #pragma unroll
        for (int b = 0; b < 2; ++b) C[a][b] = 0.0f;

      // prefetch epilogue operands (E0 static during loop; issued before poll)
      int tv = tgt[(nt_e * 16 + l15) * 256 + t];
      f32x4 e0v = *(const f32x4*)(E0 + (size_t)tv * 4096 + wgl * 32 + mi_e * 16 + (l4 << 2));
      pollT<1>(f0, lane, t);
      const char* Bb = h0slot(WA0, h0s0, h0hi, t);
      const int ksb = wv * 8;
      s16x8 P[3][4];
      #pragma unroll
      for (int d = 0; d < 2; ++d)
        #pragma unroll
        for (int q = 0; q < 4; ++q) LDP(P[d][q], Bb + ((q * 32 + ksb + d) << 10) + lane * 16);
      #pragma unroll
      for (int i = 0; i < 8; ++i) {
        const int ks = ksb + i;
        if (i < 6) {
          #pragma unroll
          for (int q = 0; q < 4; ++q) LDP(P[(i + 2) % 3][q], Bb + ((q * 32 + ks + 2) << 10) + lane * 16);
        }
        s16x8 Ah0 = ld16(smem + ((0 * 32 + ks) << 10) + lane * 16);
        s16x8 Ah1 = ld16(smem + ((1 * 32 + ks) << 10) + lane * 16);
        s16x8 Al0 = ld16(smem + ((2 * 32 + ks) << 10) + lane * 16);
        s16x8 Al1 = ld16(smem + ((3 * 32 + ks) << 10) + lane * 16);
        if (i < 6) { WAITVM(8); } else if (i == 6) { WAITVM(4); } else { WAITVM(0); }
        TRIPLE(C[0][0], Ah0, Al0, P[i % 3][0], P[i % 3][2]);
        TRIPLE(C[0][1], Ah0, Al0, P[i % 3][1], P[i % 3][3]);
        TRIPLE(C[1][0], Ah1, Al1, P[i % 3][0], P[i % 3][2]);
        TRIPLE(C[1][1], Ah1, Al1, P[i % 3][1], P[i % 3][3]);
      }

      #pragma unroll
      for (int mi = 0; mi < 2; ++mi)
        #pragma unroll
        for (int nt = 0; nt < 2; ++nt)
          *(f32x4*)(smem + PART + ((wv * 4 + mi * 2 + nt) << 10) + lane * 16) = C[mi][nt];
      __syncthreads();                             // syncA

      {
        f32x4 z = *(const f32x4*)(smem + PART + ((0 * 4 + wv) << 10) + lane * 16);
        #pragma unroll
        for (int w = 1; w < 4; ++w)
          z += *(const f32x4*)(smem + PART + ((w * 4 + wv) << 10) + lane * 16);
        z += e0v;
        float ig = 1.f / (1.f + __expf(-z[0]));
        float fg = 1.f / (1.f + __expf(-z[1]));
        float og = 1.f / (1.f + __expf(-z[3]));
        float cn = fg * cst + ig * tanhf(z[2]);
        float hn = og * tanhf(cn);
        cst = cn;
        unsigned short hb = f2bf(hn);
        unsigned short lb = f2bf(hn - bf2f(hb));
        *(short*)(smem + RP + ((0 + nt_e) * 16 + l15) * 16 + (mi_e * 4 + l4) * 2) = (short)hb;
        *(short*)(smem + RP + ((2 + nt_e) * 16 + l15) * 16 + (mi_e * 4 + l4) * 2) = (short)lb;
        if (t == 255) {
          int u = wgl * 8 + mi_e * 4 + l4, b = nt_e * 16 + l15;
          out[2097152 + b * 1024 + u] = hn;
          out[2097152 + 32768 + b * 1024 + u] = cn;
        }
      }
      __syncthreads();                             // syncB

      if (wv == 0) {
        char* hd = h0slot(WA0, h0s0, h0hi, s);
        u32x4 v = *(const u32x4*)(smem + RP + lane * 16);
        char* dst = hd + (((lane >> 4) * 32 + (wgl >> 2)) << 10) + ((wgl & 3) * 16 + l15) * 16;
        st16c(dst, v);
        asm volatile("s_waitcnt vmcnt(0)" ::: "memory");
        if (lane == 0) set_flag(f0 + wgl * 8, s);
      }
    }
  } else {
    // ---- L1: prologue — prefetch Z1a[0] = h0_0 @ Wih1 (slot 1) ----
    f32x4 zpre;
    {
      pollT<2>(f0, lane, 1);
      f32x4 C2[2][2];
      #pragma unroll
      for (int a = 0; a < 2; ++a)
        #pragma unroll
        for (int b = 0; b < 2; ++b) C2[a][b] = 0.0f;
      halfgemm8(smem, WA1, h0slot(WA0, h0s0, h0hi, 1), wgl, wv * 8, lane, C2);
      #pragma unroll
      for (int mi = 0; mi < 2; ++mi)
        #pragma unroll
        for (int nt = 0; nt < 2; ++nt)
          *(f32x4*)(smem + PART + ((wv * 4 + mi * 2 + nt) << 10) + lane * 16) = C2[mi][nt];
      __syncthreads();                             // syncC
      zpre = *(const f32x4*)(smem + PART + ((0 * 4 + wv) << 10) + lane * 16);
      #pragma unroll
      for (int w = 1; w < 4; ++w)
        zpre += *(const f32x4*)(smem + PART + ((w * 4 + wv) << 10) + lane * 16);
      __syncthreads();                             // syncD
    }

    for (int t = 0; t < 256; ++t) {
      const int s = t + 1;
      f32x4 C[2][2];
      #pragma unroll
      for (int a = 0; a < 2; ++a)
        #pragma unroll
        for (int b = 0; b < 2; ++b) C[a][b] = 0.0f;

      // ---- CRITICAL: h1_{t-1} @ Whh1 on all 4 waves ----
      pollT<1>(f1, lane, t);
      halfgemm8(smem + 65536, WA2, h1frag + (size_t)t * 131072, wgl, wv * 8, lane, C);

      #pragma unroll
      for (int mi = 0; mi < 2; ++mi)
        #pragma unroll
        for (int nt = 0; nt < 2; ++nt)
          *(f32x4*)(smem + PART + ((wv * 4 + mi * 2 + nt) << 10) + lane * 16) = C[mi][nt];
      __syncthreads();                             // syncA

      {
        f32x4 z = *(const f32x4*)(smem + PART + ((0 * 4 + wv) << 10) + lane * 16);
        #pragma unroll
        for (int w = 1; w < 4; ++w)
          z += *(const f32x4*)(smem + PART + ((w * 4 + wv) << 10) + lane * 16);
        z += zpre + b1z;
        float ig = 1.f / (1.f + __expf(-z[0]));
        float fg = 1.f / (1.f + __expf(-z[1]));
        float og = 1.f / (1.f + __expf(-z[3]));
        float cn = fg * cst + ig * tanhf(z[2]);
        float hn = og * tanhf(cn);
        cst = cn;
        unsigned short hb = f2bf(hn);
        unsigned short lb = f2bf(hn - bf2f(hb));
        *(short*)(smem + RP + ((0 + nt_e) * 16 + l15) * 16 + (mi_e * 4 + l4) * 2) = (short)hb;
        *(short*)(smem + RP + ((2 + nt_e) * 16 + l15) * 16 + (mi_e * 4 + l4) * 2) = (short)lb;
        if (t == 255) {
          int u = wgl * 8 + mi_e * 4 + l4, b = nt_e * 16 + l15;
          out[2097152 + 65536 + b * 1024 + u] = hn;
          out[2097152 + 65536 + 32768 + b * 1024 + u] = cn;
        }
      }
      __syncthreads();                             // syncB

      if (wv == 0) {
        char* hd = h1frag + (size_t)s * 131072;
        u32x4 v = *(const u32x4*)(smem + RP + lane * 16);
        char* dst = hd + (((lane >> 4) * 32 + (wgl >> 2)) << 10) + ((wgl & 3) * 16 + l15) * 16;
        st16c(dst, v);
        asm volatile("s_waitcnt vmcnt(0)" ::: "memory");
        if (lane == 0) set_flag(f1 + wgl * 8, s);
      }

      // ---- off-critical: prefetch Z1a[t+1] = h0_{t+1} @ Wih1 (slot t+2) ----
      if (t < 255) {
        pollT<2>(f0, lane, t + 2);
        f32x4 C2[2][2];
        #pragma unroll
        for (int a = 0; a < 2; ++a)
          #pragma unroll
          for (int b = 0; b < 2; ++b) C2[a][b] = 0.0f;
        halfgemm8(smem, WA1, h0slot(WA0, h0s0, h0hi, t + 2), wgl, wv * 8, lane, C2);
        #pragma unroll
        for (int mi = 0; mi < 2; ++mi)
          #pragma unroll
          for (int nt = 0; nt < 2; ++nt)
            *(f32x4*)(smem + PART + ((wv * 4 + mi * 2 + nt) << 10) + lane * 16) = C2[mi][nt];
        __syncthreads();                           // syncC
        zpre = *(const f32x4*)(smem + PART + ((0 * 4 + wv) << 10) + lane * 16);
        #pragma unroll
        for (int w = 1; w < 4; ++w)
          zpre += *(const f32x4*)(smem + PART + ((w * 4 + wv) << 10) + lane * 16);
        __syncthreads();                           // syncD
      }
    }
  }

  // ---- projection: logits[b][t][v] = h1_t @ W_out + b_out ; one t per CU ----
  // L0 wgs (finish first) take EARLY t (flags long set); L1 wgs take late t.
  {
    const int tp = isL0 ? wgl : (128 + wgl);
    pollT<32>(f1, lane, tp + 1);
    const char* A = h1frag + (size_t)(tp + 1) * 131072;
    f32x4 C[2][4];
    #pragma unroll
    for (int a = 0; a < 2; ++a)
      #pragma unroll
      for (int b = 0; b < 4; ++b) C[a][b] = 0.0f;
    s16x8 QA[4], QB[4];
    #pragma unroll
    for (int q = 0; q < 4; ++q) LDP(QA[q], A + ((q * 32 + 0) << 10) + lane * 16);
    for (int kk = 0; kk < 16; ++kk) {
      const int ks = kk * 2;
      #pragma unroll
      for (int q = 0; q < 4; ++q) LDP(QB[q], A + ((q * 32 + ks + 1) << 10) + lane * 16);
      asm volatile("s_waitcnt vmcnt(4)" ::: "memory");
      __builtin_amdgcn_sched_barrier(0);
      #pragma unroll
      for (int v4 = 0; v4 < 4; ++v4) {
        int vb = wv * 4 + v4;
        s16x8 Bh = ld16(WoutB + (((vb * 2 + 0) * 32 + ks) << 10) + lane * 16);
        s16x8 Bl = ld16(WoutB + (((vb * 2 + 1) * 32 + ks) << 10) + lane * 16);
        C[0][v4] = MF(QA[0], Bh, C[0][v4]); C[0][v4] = MF(QA[0], Bl, C[0][v4]); C[0][v4] = MF(QA[2], Bh, C[0][v4]);
        C[1][v4] = MF(QA[1], Bh, C[1][v4]); C[1][v4] = MF(QA[1], Bl, C[1][v4]); C[1][v4] = MF(QA[3], Bh, C[1][v4]);
      }
      if (kk < 15) {
        #pragma unroll
        for (int q = 0; q < 4; ++q) LDP(QA[q], A + ((q * 32 + ks + 2) << 10) + lane * 16);
        asm volatile("s_waitcnt vmcnt(4)" ::: "memory");
      } else {
        asm volatile("s_waitcnt vmcnt(0)" ::: "memory");
      }
      __builtin_amdgcn_sched_barrier(0);
      #pragma unroll
      for (int v4 = 0; v4 < 4; ++v4) {
        int vb = wv * 4 + v4;
        s16x8 Bh = ld16(WoutB + (((vb * 2 + 0) * 32 + ks + 1) << 10) + lane * 16);
        s16x8 Bl = ld16(WoutB + (((vb * 2 + 1) * 32 + ks + 1) << 10) + lane * 16);
        C[0][v4] = MF(QB[0], Bh, C[0][v4]); C[0][v4] = MF(QB[0], Bl, C[0][v4]); C[0][v4] = MF(QB[2], Bh, C[0][v4]);
        C[1][v4] = MF(QB[1], Bh, C[1][v4]); C[1][v4] = MF(QB[1], Bl, C[1][v4]); C[1][v4] = MF(QB[3], Bh, C[1][v4]);
      }
    }
    #pragma unroll
    for (int nt = 0; nt < 2; ++nt)
      #pragma unroll
      for (int v4 = 0; v4 < 4; ++v4) {
        int v = (wv * 4 + v4) * 16 + l15;
        float bo = b_out[v];
        #pragma unroll
        for (int r = 0; r < 4; ++r) {
          int b = nt * 16 + l4 * 4 + r;
          out[((size_t)b * 256 + tp) * 256 + v] = C[nt][v4][r] + bo;
        }
      }
  }
}

extern "C" void kernel_launch(void* const* d_in, const int* in_sizes, int n_in,
                              void* d_out, int out_size, void* d_ws, size_t ws_size,
                              hipStream_t stream) {
  const int*   targets = (const int*)d_in[1];
  const float* h0_in   = (const float*)d_in[2];
  const float* c0_in   = (const float*)d_in[3];
  const float* h1_in   = (const float*)d_in[4];
  const float* c1_in   = (const float*)d_in[5];
  const float* emb     = (const float*)d_in[6];
  const float* W_ih0   = (const float*)d_in[7];
  const float* W_hh0   = (const float*)d_in[8];
  const float* b0      = (const float*)d_in[9];
  const float* W_ih1   = (const float*)d_in[10];
  const float* W_hh1   = (const float*)d_in[11];
  const float* b1      = (const float*)d_in[12];
  const float* W_out   = (const float*)d_in[13];
  const float* b_out   = (const float*)d_in[14];
  float* out = (float*)d_out;

  char* ws = (char*)d_ws;
  char*  WA0    = ws;                         // Whh0 A-frags hi/lo 16MB; becomes h0 slots 1..128
  char*  WA1    = ws + 16777216;              // Wih1 (hi staged, lo streamed)
  char*  WA2    = ws + 33554432;              // Whh1
  char*  WoutB  = ws + 50331648;              // W_out B-frags, 1MB
  char*  embB   = ws + 51380224;              // emb B-frags, 1MB
  float* E0     = (float*)(ws + 52428800);    // 4MB f32
  float* b1i    = (float*)(ws + 56623104);    // 16KB
  int*   f0     = (int*)(ws + 56639488);      // flag array, 4KB (128 x stride 32B)
  int*   f1     = (int*)(ws + 56643584);      // flag array, 4KB
  char*  h0s0   = ws + 56647680;              // h0 slot 0, 128KB
  char*  h0hi   = ws + 56778752;              // h0 slots 129..256, 16MB
  char*  h1frag = ws + 73555968;              // 257 slots x 128KB (~33.7MB) -> end ~102.3MB
  char*  WAi0   = h1frag + 16777216;          // Wih0 A-frags alias h1 slots 128..255
                                              // (read via sc-loads at E0; slot 128 written step 127)

  prep_misc <<<18,   256, 0, stream>>>(b1, b1i, f0, f1);
  prep_wfrag<<<8192, 256, 0, stream>>>(W_hh0, W_ih1, W_hh1, W_ih0, WA0, WA1, WA2, WAi0);
  prep_bfrag<<<256,  256, 0, stream>>>(emb, W_out, embB, WoutB);
  prep_hinit<<<32,   256, 0, stream>>>(h0_in, h1_in, h0s0, h1frag);

  hipFuncSetAttribute(reinterpret_cast<const void*>(lstm_persist),
                      hipFuncAttributeMaxDynamicSharedMemorySize, 148480);
  lstm_persist<<<256, 256, 148480, stream>>>(
      targets, c0_in, c1_in, b0, b_out,
      WA0, WA1, WA2, WAi0, WoutB, embB,
      E0, b1i, h0s0, h0hi, h1frag, f0, f1, out);
}